// Round 1
// baseline (2860.236 us; speedup 1.0000x reference)
//
#include <hip/hip_runtime.h>
#include <cstddef>

// EdgeDegreeEmbedding fused kernel, round 0 (correctness-first, f32 VALU).
//
// Pipeline per edge e:
//   x[384] = concat(edge_embeds[e], embed_table[species[senders[e]]][0:128],
//                                   embed_table[species[receivers[e]]][128:256])
//   h0 = silu(LN(x @ W0 + b0))          (384 -> 128)
//   h1 = silu(LN(h0 @ W1 + b1))         (128 -> 128)
//   f  = (h1 @ W2 + b2) * (1/RESCALE)   (128 -> 160 = [5 m][32 ch])
//   out[recv[e]][k][ch] += sum_m wigner[e][k][m] * f[m][ch]   (k < 25, m < 5)
//
// Work assignment: 256 threads handle EB=32 edges. GEMM stages are
// register-blocked: thread owns one output column and 16 rows, W streamed
// from global (L2-resident), X read from LDS with same-address broadcast
// (free). Aggregation via device-scope f32 atomicAdd (random receivers).
//
// Roadmap (later rounds): bf16 MFMA for the 3 GEMMs (f32 VALU is the
// ~370us floor here), CSR-binned aggregation to remove 256M atomics.

#define NTHREADS 256
#define EB 32
#define DIN 384
#define HDIM 128
#define NOUT 160
#define NKF 25
#define WIG_LD 19

__device__ __forceinline__ void ln_silu(float (*Bx)[HDIM], const float* __restrict__ s,
                                        const float* __restrict__ b, int t)
{
    // 8 threads per row, 16 contiguous channels each.
    const int r = t >> 3;
    const int j = t & 7;
    float v[16];
    float sum = 0.f, sq = 0.f;
#pragma unroll
    for (int q = 0; q < 16; ++q) {
        v[q] = Bx[r][j * 16 + q];
        sum += v[q];
        sq = fmaf(v[q], v[q], sq);
    }
#pragma unroll
    for (int m = 1; m < 8; m <<= 1) {
        sum += __shfl_xor(sum, m, 64);
        sq  += __shfl_xor(sq,  m, 64);
    }
    const float mu   = sum * (1.f / HDIM);
    const float var  = sq * (1.f / HDIM) - mu * mu;
    const float rstd = rsqrtf(var + 1e-6f);
#pragma unroll
    for (int q = 0; q < 16; ++q) {
        const int cc = j * 16 + q;
        const float y = (v[q] - mu) * rstd * s[cc] + b[cc];
        Bx[r][cc] = y / (1.f + __expf(-y));   // silu
    }
}

__global__ __launch_bounds__(NTHREADS, 2)
void edge_fused_kernel(
    const int* __restrict__ species,          // [N]
    const float* __restrict__ edge_embeds,    // [E,128]
    const int* __restrict__ senders,          // [E]
    const int* __restrict__ receivers,        // [E]
    const float* __restrict__ wigner,         // [E,25,19]
    const float* __restrict__ embed_table,    // [90,256]
    const float* __restrict__ W0, const float* __restrict__ b0,
    const float* __restrict__ ln0s, const float* __restrict__ ln0b,
    const float* __restrict__ W1, const float* __restrict__ b1,
    const float* __restrict__ ln1s, const float* __restrict__ ln1b,
    const float* __restrict__ W2, const float* __restrict__ b2,
    float* __restrict__ out,                  // [N,25,32]
    int n_edges)
{
    __shared__ float A[EB][DIN];     // 48 KB; reused later as F[EB][NOUT]
    __shared__ float Bx[EB][HDIM];   // 16 KB
    __shared__ int sSpec[EB];
    __shared__ int rSpec[EB];
    __shared__ int rNode[EB];

    const int t = threadIdx.x;
    const int e0 = blockIdx.x * EB;

    if (t < EB) {
        const int e = e0 + t;
        int s = 0, r = 0;
        if (e < n_edges) { s = senders[e]; r = receivers[e]; }
        sSpec[t] = species[s];
        rSpec[t] = species[r];
        rNode[t] = r;
    }
    __syncthreads();

    // ---- load X = concat(edge, s_emb, r_emb) into LDS ----
    for (int idx = t; idx < EB * DIN; idx += NTHREADS) {
        const int r = idx / DIN;
        const int i = idx - r * DIN;
        const int e = e0 + r;
        float v = 0.f;
        if (e < n_edges) {
            if (i < HDIM)
                v = edge_embeds[(size_t)e * HDIM + i];
            else if (i < 2 * HDIM)
                v = embed_table[(size_t)sSpec[r] * 256 + (i - HDIM)];
            else
                v = embed_table[(size_t)rSpec[r] * 256 + HDIM + (i - 2 * HDIM)];
        }
        A[r][i] = v;
    }
    __syncthreads();

    const int c = t & (HDIM - 1);   // output column 0..127
    const int g = t >> 7;           // row-group 0..1 (16 rows each)
    float acc[16];

    // ---- stage 1: H0 = X @ W0 + b0 ----
#pragma unroll
    for (int q = 0; q < 16; ++q) acc[q] = 0.f;
    for (int it = 0; it < DIN / 4; ++it) {
        const float wa = W0[(4 * it + 0) * HDIM + c];
        const float wb = W0[(4 * it + 1) * HDIM + c];
        const float wc = W0[(4 * it + 2) * HDIM + c];
        const float wd = W0[(4 * it + 3) * HDIM + c];
#pragma unroll
        for (int q = 0; q < 16; ++q) {
            const float4 x4 = *reinterpret_cast<const float4*>(&A[g * 16 + q][4 * it]);
            acc[q] = fmaf(x4.x, wa, acc[q]);
            acc[q] = fmaf(x4.y, wb, acc[q]);
            acc[q] = fmaf(x4.z, wc, acc[q]);
            acc[q] = fmaf(x4.w, wd, acc[q]);
        }
    }
    {
        const float bb = b0[c];
#pragma unroll
        for (int q = 0; q < 16; ++q) Bx[g * 16 + q][c] = acc[q] + bb;
    }
    __syncthreads();
    ln_silu(Bx, ln0s, ln0b, t);
    __syncthreads();

    // ---- stage 2: H1 = H0n @ W1 + b1 ----
#pragma unroll
    for (int q = 0; q < 16; ++q) acc[q] = 0.f;
    for (int it = 0; it < HDIM / 4; ++it) {
        const float wa = W1[(4 * it + 0) * HDIM + c];
        const float wb = W1[(4 * it + 1) * HDIM + c];
        const float wc = W1[(4 * it + 2) * HDIM + c];
        const float wd = W1[(4 * it + 3) * HDIM + c];
#pragma unroll
        for (int q = 0; q < 16; ++q) {
            const float4 x4 = *reinterpret_cast<const float4*>(&Bx[g * 16 + q][4 * it]);
            acc[q] = fmaf(x4.x, wa, acc[q]);
            acc[q] = fmaf(x4.y, wb, acc[q]);
            acc[q] = fmaf(x4.z, wc, acc[q]);
            acc[q] = fmaf(x4.w, wd, acc[q]);
        }
    }
    __syncthreads();   // all reads of Bx done before overwrite
    {
        const float bb = b1[c];
#pragma unroll
        for (int q = 0; q < 16; ++q) Bx[g * 16 + q][c] = acc[q] + bb;
    }
    __syncthreads();
    ln_silu(Bx, ln1s, ln1b, t);
    __syncthreads();

    // ---- stage 3: F = (H1n @ W2 + b2) * 0.2, into A's storage ----
    float* F = &A[0][0];   // [EB][NOUT] flat

    {   // columns 0..127: same mapping as stages 1/2
        float a2[16];
#pragma unroll
        for (int q = 0; q < 16; ++q) a2[q] = 0.f;
        for (int it = 0; it < HDIM / 4; ++it) {
            const float wa = W2[(4 * it + 0) * NOUT + c];
            const float wb = W2[(4 * it + 1) * NOUT + c];
            const float wc = W2[(4 * it + 2) * NOUT + c];
            const float wd = W2[(4 * it + 3) * NOUT + c];
#pragma unroll
            for (int q = 0; q < 16; ++q) {
                const float4 x4 = *reinterpret_cast<const float4*>(&Bx[g * 16 + q][4 * it]);
                a2[q] = fmaf(x4.x, wa, a2[q]);
                a2[q] = fmaf(x4.y, wb, a2[q]);
                a2[q] = fmaf(x4.z, wc, a2[q]);
                a2[q] = fmaf(x4.w, wd, a2[q]);
            }
        }
        const float bb = b2[c];
#pragma unroll
        for (int q = 0; q < 16; ++q)
            F[(g * 16 + q) * NOUT + c] = (a2[q] + bb) * 0.2f;
    }
    {   // columns 128..159: 32 cols, 8 row-groups of 4 rows
        const int c2 = HDIM + (t & 31);
        const int g8 = t >> 5;
        float a2[4] = {0.f, 0.f, 0.f, 0.f};
        for (int it = 0; it < HDIM / 4; ++it) {
            const float wa = W2[(4 * it + 0) * NOUT + c2];
            const float wb = W2[(4 * it + 1) * NOUT + c2];
            const float wc = W2[(4 * it + 2) * NOUT + c2];
            const float wd = W2[(4 * it + 3) * NOUT + c2];
#pragma unroll
            for (int q = 0; q < 4; ++q) {
                const float4 x4 = *reinterpret_cast<const float4*>(&Bx[g8 * 4 + q][4 * it]);
                a2[q] = fmaf(x4.x, wa, a2[q]);
                a2[q] = fmaf(x4.y, wb, a2[q]);
                a2[q] = fmaf(x4.z, wc, a2[q]);
                a2[q] = fmaf(x4.w, wd, a2[q]);
            }
        }
        const float bb = b2[c2];
#pragma unroll
        for (int q = 0; q < 4; ++q)
            F[(g8 * 4 + q) * NOUT + c2] = (a2[q] + bb) * 0.2f;
    }
    __syncthreads();

    // ---- wigner rotation + scatter-add ----
    for (int r = 0; r < EB; ++r) {
        const int e = e0 + r;
        if (e >= n_edges) break;
        const float* __restrict__ wrow = wigner + (size_t)e * (NKF * WIG_LD);
        float* __restrict__ orow = out + (size_t)rNode[r] * (NKF * 32);
        const float* __restrict__ Fr = F + r * NOUT;
#pragma unroll
        for (int jj = 0; jj < 4; ++jj) {
            const int p = t + NTHREADS * jj;
            if (p < NKF * 32) {
                const int k = p >> 5;
                const int ch = p & 31;
                float val = 0.f;
#pragma unroll
                for (int m = 0; m < 5; ++m)
                    val = fmaf(wrow[k * WIG_LD + m], Fr[m * 32 + ch], val);
                atomicAdd(&orow[p], val);
            }
        }
    }
}

extern "C" void kernel_launch(void* const* d_in, const int* in_sizes, int n_in,
                              void* d_out, int out_size, void* d_ws, size_t ws_size,
                              hipStream_t stream)
{
    const int*   species     = (const int*)d_in[0];
    const float* edge_embeds = (const float*)d_in[1];
    const int*   senders     = (const int*)d_in[2];
    const int*   receivers   = (const int*)d_in[3];
    const float* wigner      = (const float*)d_in[4];
    const float* embed_table = (const float*)d_in[5];
    const float* W0 = (const float*)d_in[6];
    const float* b0 = (const float*)d_in[7];
    const float* ln0s = (const float*)d_in[8];
    const float* ln0b = (const float*)d_in[9];
    const float* W1 = (const float*)d_in[10];
    const float* b1 = (const float*)d_in[11];
    const float* ln1s = (const float*)d_in[12];
    const float* ln1b = (const float*)d_in[13];
    const float* W2 = (const float*)d_in[14];
    const float* b2 = (const float*)d_in[15];
    float* out = (float*)d_out;

    const int n_edges = in_sizes[2];

    // Atomics accumulate into d_out: must zero it every call (harness does
    // not re-poison between timed replays).
    hipMemsetAsync(out, 0, (size_t)out_size * sizeof(float), stream);

    const int nblocks = (n_edges + EB - 1) / EB;
    hipLaunchKernelGGL(edge_fused_kernel, dim3(nblocks), dim3(NTHREADS), 0, stream,
                       species, edge_embeds, senders, receivers, wigner, embed_table,
                       W0, b0, ln0s, ln0b, W1, b1, ln1s, ln1b, W2, b2, out, n_edges);
}

// Round 2
// 1329.411 us; speedup vs baseline: 2.1515x; 2.1515x over previous
//
#include <hip/hip_runtime.h>
#include <cstddef>

// EdgeDegreeEmbedding, round 1.
//  - MLP kernel: 4x4 register tiles per thread (LDS-issue fix), writes F[E,160] to ws.
//  - CSR build in ws (hist -> scan -> scatter), then gather-aggregation kernel
//    (one block per node) does the 25x5 wigner contraction with plain stores.
//  - Fallback to round-0 fused atomic kernel if ws too small.

#define NTHREADS 256
#define EB 32
#define DIN 384
#define HDIM 128
#define NOUT 160
#define NKF 25
#define WIG_LD 19
#define WIG_ROW 475   // 25*19

// ---------------------------------------------------------------- ln+silu
__device__ __forceinline__ void ln_silu(float (*Bx)[HDIM], const float* __restrict__ s,
                                        const float* __restrict__ b, int t)
{
    const int r = t >> 3;
    const int j = t & 7;
    float v[16];
    float sum = 0.f, sq = 0.f;
#pragma unroll
    for (int q = 0; q < 16; ++q) {
        v[q] = Bx[r][j * 16 + q];
        sum += v[q];
        sq = fmaf(v[q], v[q], sq);
    }
#pragma unroll
    for (int m = 1; m < 8; m <<= 1) {
        sum += __shfl_xor(sum, m, 64);
        sq  += __shfl_xor(sq,  m, 64);
    }
    const float mu   = sum * (1.f / HDIM);
    const float var  = sq * (1.f / HDIM) - mu * mu;
    const float rstd = rsqrtf(var + 1e-6f);
#pragma unroll
    for (int q = 0; q < 16; ++q) {
        const int cc = j * 16 + q;
        const float y = (v[q] - mu) * rstd * s[cc] + b[cc];
        Bx[r][cc] = y / (1.f + __expf(-y));
    }
}

// ---------------------------------------------------------------- MLP -> F
__global__ __launch_bounds__(NTHREADS, 2)
void mlp_kernel(
    const int* __restrict__ species,
    const float* __restrict__ edge_embeds,
    const int* __restrict__ senders,
    const int* __restrict__ receivers,
    const float* __restrict__ embed_table,
    const float* __restrict__ W0, const float* __restrict__ b0,
    const float* __restrict__ ln0s, const float* __restrict__ ln0b,
    const float* __restrict__ W1, const float* __restrict__ b1,
    const float* __restrict__ ln1s, const float* __restrict__ ln1b,
    const float* __restrict__ W2, const float* __restrict__ b2,
    float* __restrict__ F,                    // [E,160]
    int n_edges)
{
    __shared__ float A[EB][DIN];     // 48 KB: X, later reused as H1 [EB][128]
    __shared__ float Bx[EB][HDIM];   // 16 KB: H0
    __shared__ int sSpec[EB];
    __shared__ int rSpec[EB];

    const int t = threadIdx.x;
    const int e0 = blockIdx.x * EB;

    if (t < EB) {
        const int e = e0 + t;
        int s = 0, r = 0;
        if (e < n_edges) { s = senders[e]; r = receivers[e]; }
        sSpec[t] = species[s];
        rSpec[t] = species[r];
    }
    __syncthreads();

    // ---- load X (vectorized float4) ----
    for (int q4 = t; q4 < EB * (DIN / 4); q4 += NTHREADS) {
        const int r = q4 / (DIN / 4);
        const int i4 = q4 - r * (DIN / 4);
        const int i = 4 * i4;
        const int e = e0 + r;
        float4 v = make_float4(0.f, 0.f, 0.f, 0.f);
        if (e < n_edges) {
            if (i < HDIM)
                v = *reinterpret_cast<const float4*>(&edge_embeds[(size_t)e * HDIM + i]);
            else if (i < 2 * HDIM)
                v = *reinterpret_cast<const float4*>(&embed_table[(size_t)sSpec[r] * 256 + (i - HDIM)]);
            else
                v = *reinterpret_cast<const float4*>(&embed_table[(size_t)rSpec[r] * 256 + HDIM + (i - 2 * HDIM)]);
        }
        *reinterpret_cast<float4*>(&A[r][i]) = v;
    }
    __syncthreads();

    const int cg = t & 31;   // col-group: cols 4cg..4cg+3
    const int rg = t >> 5;   // row-group: rows 4rg..4rg+3
    float acc[4][4];

    // ---- stage 1: H0 = X @ W0 + b0 ----
#pragma unroll
    for (int q = 0; q < 4; ++q)
#pragma unroll
        for (int c = 0; c < 4; ++c) acc[q][c] = 0.f;

    for (int kk = 0; kk < DIN / 4; ++kk) {
        float4 x[4];
#pragma unroll
        for (int q = 0; q < 4; ++q)
            x[q] = *reinterpret_cast<const float4*>(&A[4 * rg + q][4 * kk]);
        float4 w[4];
#pragma unroll
        for (int j = 0; j < 4; ++j)
            w[j] = *reinterpret_cast<const float4*>(&W0[(size_t)(4 * kk + j) * HDIM + 4 * cg]);
#pragma unroll
        for (int q = 0; q < 4; ++q) {
            acc[q][0] = fmaf(x[q].x, w[0].x, fmaf(x[q].y, w[1].x, fmaf(x[q].z, w[2].x, fmaf(x[q].w, w[3].x, acc[q][0]))));
            acc[q][1] = fmaf(x[q].x, w[0].y, fmaf(x[q].y, w[1].y, fmaf(x[q].z, w[2].y, fmaf(x[q].w, w[3].y, acc[q][1]))));
            acc[q][2] = fmaf(x[q].x, w[0].z, fmaf(x[q].y, w[1].z, fmaf(x[q].z, w[2].z, fmaf(x[q].w, w[3].z, acc[q][2]))));
            acc[q][3] = fmaf(x[q].x, w[0].w, fmaf(x[q].y, w[1].w, fmaf(x[q].z, w[2].w, fmaf(x[q].w, w[3].w, acc[q][3]))));
        }
    }
    {
        const float4 bb = *reinterpret_cast<const float4*>(&b0[4 * cg]);
#pragma unroll
        for (int q = 0; q < 4; ++q) {
            float4 o = make_float4(acc[q][0] + bb.x, acc[q][1] + bb.y,
                                   acc[q][2] + bb.z, acc[q][3] + bb.w);
            *reinterpret_cast<float4*>(&Bx[4 * rg + q][4 * cg]) = o;
        }
    }
    __syncthreads();
    ln_silu(Bx, ln0s, ln0b, t);
    __syncthreads();

    // ---- stage 2: H1 = H0n @ W1 + b1, into A's storage ----
    float* H1 = &A[0][0];   // [EB][128] flat
#pragma unroll
    for (int q = 0; q < 4; ++q)
#pragma unroll
        for (int c = 0; c < 4; ++c) acc[q][c] = 0.f;

    for (int kk = 0; kk < HDIM / 4; ++kk) {
        float4 x[4];
#pragma unroll
        for (int q = 0; q < 4; ++q)
            x[q] = *reinterpret_cast<const float4*>(&Bx[4 * rg + q][4 * kk]);
        float4 w[4];
#pragma unroll
        for (int j = 0; j < 4; ++j)
            w[j] = *reinterpret_cast<const float4*>(&W1[(size_t)(4 * kk + j) * HDIM + 4 * cg]);
#pragma unroll
        for (int q = 0; q < 4; ++q) {
            acc[q][0] = fmaf(x[q].x, w[0].x, fmaf(x[q].y, w[1].x, fmaf(x[q].z, w[2].x, fmaf(x[q].w, w[3].x, acc[q][0]))));
            acc[q][1] = fmaf(x[q].x, w[0].y, fmaf(x[q].y, w[1].y, fmaf(x[q].z, w[2].y, fmaf(x[q].w, w[3].y, acc[q][1]))));
            acc[q][2] = fmaf(x[q].x, w[0].z, fmaf(x[q].y, w[1].z, fmaf(x[q].z, w[2].z, fmaf(x[q].w, w[3].z, acc[q][2]))));
            acc[q][3] = fmaf(x[q].x, w[0].w, fmaf(x[q].y, w[1].w, fmaf(x[q].z, w[2].w, fmaf(x[q].w, w[3].w, acc[q][3]))));
        }
    }
    {
        const float4 bb = *reinterpret_cast<const float4*>(&b1[4 * cg]);
#pragma unroll
        for (int q = 0; q < 4; ++q) {
            float4 o = make_float4(acc[q][0] + bb.x, acc[q][1] + bb.y,
                                   acc[q][2] + bb.z, acc[q][3] + bb.w);
            *reinterpret_cast<float4*>(&H1[(4 * rg + q) * HDIM + 4 * cg]) = o;
        }
    }
    __syncthreads();
    ln_silu(reinterpret_cast<float (*)[HDIM]>(H1), ln1s, ln1b, t);
    __syncthreads();

    // ---- stage 3: F = (H1n @ W2 + b2) * 0.2, straight to global ----
    // main: cols 0..127 as 4x4 tiles; tail: col 128+(t&31), rows 4rg..4rg+3
    const int ctail = HDIM + (t & 31);
    float acc2[4] = {0.f, 0.f, 0.f, 0.f};
#pragma unroll
    for (int q = 0; q < 4; ++q)
#pragma unroll
        for (int c = 0; c < 4; ++c) acc[q][c] = 0.f;

    for (int kk = 0; kk < HDIM / 4; ++kk) {
        float4 x[4];
#pragma unroll
        for (int q = 0; q < 4; ++q)
            x[q] = *reinterpret_cast<const float4*>(&H1[(4 * rg + q) * HDIM + 4 * kk]);
        float4 w[4];
        float wt[4];
#pragma unroll
        for (int j = 0; j < 4; ++j) {
            w[j] = *reinterpret_cast<const float4*>(&W2[(size_t)(4 * kk + j) * NOUT + 4 * cg]);
            wt[j] = W2[(size_t)(4 * kk + j) * NOUT + ctail];
        }
#pragma unroll
        for (int q = 0; q < 4; ++q) {
            acc[q][0] = fmaf(x[q].x, w[0].x, fmaf(x[q].y, w[1].x, fmaf(x[q].z, w[2].x, fmaf(x[q].w, w[3].x, acc[q][0]))));
            acc[q][1] = fmaf(x[q].x, w[0].y, fmaf(x[q].y, w[1].y, fmaf(x[q].z, w[2].y, fmaf(x[q].w, w[3].y, acc[q][1]))));
            acc[q][2] = fmaf(x[q].x, w[0].z, fmaf(x[q].y, w[1].z, fmaf(x[q].z, w[2].z, fmaf(x[q].w, w[3].z, acc[q][2]))));
            acc[q][3] = fmaf(x[q].x, w[0].w, fmaf(x[q].y, w[1].w, fmaf(x[q].z, w[2].w, fmaf(x[q].w, w[3].w, acc[q][3]))));
            acc2[q]   = fmaf(x[q].x, wt[0], fmaf(x[q].y, wt[1], fmaf(x[q].z, wt[2], fmaf(x[q].w, wt[3], acc2[q]))));
        }
    }
    {
        const float4 bb = *reinterpret_cast<const float4*>(&b2[4 * cg]);
        const float bt = b2[ctail];
#pragma unroll
        for (int q = 0; q < 4; ++q) {
            const int e = e0 + 4 * rg + q;
            if (e < n_edges) {
                float4 o = make_float4((acc[q][0] + bb.x) * 0.2f, (acc[q][1] + bb.y) * 0.2f,
                                       (acc[q][2] + bb.z) * 0.2f, (acc[q][3] + bb.w) * 0.2f);
                *reinterpret_cast<float4*>(&F[(size_t)e * NOUT + 4 * cg]) = o;
                F[(size_t)e * NOUT + ctail] = (acc2[q] + bt) * 0.2f;
            }
        }
    }
}

// ---------------------------------------------------------------- CSR build
__global__ void hist_kernel(const int* __restrict__ recv, int* __restrict__ cnt, int n_edges)
{
    const int e = blockIdx.x * 256 + threadIdx.x;
    if (e < n_edges) atomicAdd(&cnt[recv[e]], 1);
}

#define SCAN_T 1024
#define SCAN_CH 20   // covers up to 20480 nodes
__global__ __launch_bounds__(SCAN_T)
void scan_kernel(const int* __restrict__ cnt, int* __restrict__ offsets, int n_nodes)
{
    __shared__ int waveSum[SCAN_T / 64];
    const int t = threadIdx.x;
    const int base = t * SCAN_CH;
    int local[SCAN_CH];
    int s = 0;
#pragma unroll
    for (int j = 0; j < SCAN_CH; ++j) {
        const int v = (base + j < n_nodes) ? cnt[base + j] : 0;
        local[j] = s;
        s += v;
    }
    const int lane = t & 63;
    int incl = s;
#pragma unroll
    for (int d = 1; d < 64; d <<= 1) {
        const int u = __shfl_up(incl, d, 64);
        if (lane >= d) incl += u;
    }
    if (lane == 63) waveSum[t >> 6] = incl;
    __syncthreads();
    if (t < SCAN_T / 64) {
        const int v = waveSum[t];
        int incl2 = v;
#pragma unroll
        for (int d = 1; d < SCAN_T / 64; d <<= 1) {
            const int u = __shfl_up(incl2, d, 64);
            if (lane >= d) incl2 += u;
        }
        waveSum[t] = incl2 - v;   // exclusive wave prefix
    }
    __syncthreads();
    const int threadExcl = waveSum[t >> 6] + (incl - s);
#pragma unroll
    for (int j = 0; j < SCAN_CH; ++j)
        if (base + j < n_nodes) offsets[base + j] = threadExcl + local[j];
    if (t == SCAN_T - 1) offsets[n_nodes] = threadExcl + s;
}

__global__ void scatter_kernel(const int* __restrict__ recv, int* __restrict__ cursor,
                               int* __restrict__ elist, int n_edges)
{
    const int e = blockIdx.x * 256 + threadIdx.x;
    if (e < n_edges) {
        const int p = atomicAdd(&cursor[recv[e]], 1);
        elist[p] = e;
    }
}

// ---------------------------------------------------------------- aggregation
__global__ __launch_bounds__(256)
void agg_kernel(const float* __restrict__ wigner,   // [E,25,19]
                const float* __restrict__ F,        // [E,160]
                const int* __restrict__ offsets,
                const int* __restrict__ elist,
                float* __restrict__ out)            // [N,25,32]
{
    const int n = blockIdx.x;
    const int t = threadIdx.x;
    __shared__ float wigS[2][128];   // 125 used: [k*5+m]
    __shared__ float Fe[2][NOUT];

    const int beg = offsets[n];
    const int end = offsets[n + 1];

    const int ch = t & 31;
    const int k0 = t >> 5;
    float acc0 = 0.f, acc1 = 0.f, acc2 = 0.f, acc3 = 0.f;

    if (beg < end) {   // prefetch first edge
        const int e = elist[beg];
        if (t < 125) wigS[0][t] = wigner[(size_t)e * WIG_ROW + (t / 5) * WIG_LD + (t % 5)];
        if (t >= 128 && t < 168)
            *reinterpret_cast<float4*>(&Fe[0][4 * (t - 128)]) =
                *reinterpret_cast<const float4*>(&F[(size_t)e * NOUT + 4 * (t - 128)]);
    }

    int buf = 0;
    for (int i = beg; i < end; ++i) {
        __syncthreads();
        if (i + 1 < end) {
            const int e = elist[i + 1];
            if (t < 125) wigS[buf ^ 1][t] = wigner[(size_t)e * WIG_ROW + (t / 5) * WIG_LD + (t % 5)];
            if (t >= 128 && t < 168)
                *reinterpret_cast<float4*>(&Fe[buf ^ 1][4 * (t - 128)]) =
                    *reinterpret_cast<const float4*>(&F[(size_t)e * NOUT + 4 * (t - 128)]);
        }
        const float f0 = Fe[buf][ch];
        const float f1 = Fe[buf][32 + ch];
        const float f2 = Fe[buf][64 + ch];
        const float f3 = Fe[buf][96 + ch];
        const float f4 = Fe[buf][128 + ch];
        const float* wp = &wigS[buf][0];
        {
            const float* w = wp + k0 * 5;
            acc0 += w[0] * f0 + w[1] * f1 + w[2] * f2 + w[3] * f3 + w[4] * f4;
        }
        {
            const float* w = wp + (k0 + 8) * 5;
            acc1 += w[0] * f0 + w[1] * f1 + w[2] * f2 + w[3] * f3 + w[4] * f4;
        }
        {
            const float* w = wp + (k0 + 16) * 5;
            acc2 += w[0] * f0 + w[1] * f1 + w[2] * f2 + w[3] * f3 + w[4] * f4;
        }
        if (t < 32) {
            const float* w = wp + 24 * 5;
            acc3 += w[0] * f0 + w[1] * f1 + w[2] * f2 + w[3] * f3 + w[4] * f4;
        }
        buf ^= 1;
    }

    float* orow = out + (size_t)n * (NKF * 32);
    orow[t] = acc0;
    orow[t + 256] = acc1;
    orow[t + 512] = acc2;
    if (t < 32) orow[t + 768] = acc3;
}

// ---------------------------------------------------------------- round-0 fallback
__global__ __launch_bounds__(NTHREADS, 2)
void edge_fused_kernel(
    const int* __restrict__ species, const float* __restrict__ edge_embeds,
    const int* __restrict__ senders, const int* __restrict__ receivers,
    const float* __restrict__ wigner, const float* __restrict__ embed_table,
    const float* __restrict__ W0, const float* __restrict__ b0,
    const float* __restrict__ ln0s, const float* __restrict__ ln0b,
    const float* __restrict__ W1, const float* __restrict__ b1,
    const float* __restrict__ ln1s, const float* __restrict__ ln1b,
    const float* __restrict__ W2, const float* __restrict__ b2,
    float* __restrict__ out, int n_edges)
{
    __shared__ float A[EB][DIN];
    __shared__ float Bx[EB][HDIM];
    __shared__ int sSpec[EB], rSpec[EB], rNode[EB];
    const int t = threadIdx.x;
    const int e0 = blockIdx.x * EB;
    if (t < EB) {
        const int e = e0 + t;
        int s = 0, r = 0;
        if (e < n_edges) { s = senders[e]; r = receivers[e]; }
        sSpec[t] = species[s]; rSpec[t] = species[r]; rNode[t] = r;
    }
    __syncthreads();
    for (int idx = t; idx < EB * DIN; idx += NTHREADS) {
        const int r = idx / DIN;
        const int i = idx - r * DIN;
        const int e = e0 + r;
        float v = 0.f;
        if (e < n_edges) {
            if (i < HDIM) v = edge_embeds[(size_t)e * HDIM + i];
            else if (i < 2 * HDIM) v = embed_table[(size_t)sSpec[r] * 256 + (i - HDIM)];
            else v = embed_table[(size_t)rSpec[r] * 256 + HDIM + (i - 2 * HDIM)];
        }
        A[r][i] = v;
    }
    __syncthreads();
    const int c = t & (HDIM - 1);
    const int g = t >> 7;
    float acc[16];
#pragma unroll
    for (int q = 0; q < 16; ++q) acc[q] = 0.f;
    for (int it = 0; it < DIN / 4; ++it) {
        const float wa = W0[(4 * it + 0) * HDIM + c], wb = W0[(4 * it + 1) * HDIM + c];
        const float wc = W0[(4 * it + 2) * HDIM + c], wd = W0[(4 * it + 3) * HDIM + c];
#pragma unroll
        for (int q = 0; q < 16; ++q) {
            const float4 x4 = *reinterpret_cast<const float4*>(&A[g * 16 + q][4 * it]);
            acc[q] = fmaf(x4.x, wa, fmaf(x4.y, wb, fmaf(x4.z, wc, fmaf(x4.w, wd, acc[q]))));
        }
    }
    { const float bb = b0[c];
#pragma unroll
      for (int q = 0; q < 16; ++q) Bx[g * 16 + q][c] = acc[q] + bb; }
    __syncthreads(); ln_silu(Bx, ln0s, ln0b, t); __syncthreads();
#pragma unroll
    for (int q = 0; q < 16; ++q) acc[q] = 0.f;
    for (int it = 0; it < HDIM / 4; ++it) {
        const float wa = W1[(4 * it + 0) * HDIM + c], wb = W1[(4 * it + 1) * HDIM + c];
        const float wc = W1[(4 * it + 2) * HDIM + c], wd = W1[(4 * it + 3) * HDIM + c];
#pragma unroll
        for (int q = 0; q < 16; ++q) {
            const float4 x4 = *reinterpret_cast<const float4*>(&Bx[g * 16 + q][4 * it]);
            acc[q] = fmaf(x4.x, wa, fmaf(x4.y, wb, fmaf(x4.z, wc, fmaf(x4.w, wd, acc[q]))));
        }
    }
    __syncthreads();
    { const float bb = b1[c];
#pragma unroll
      for (int q = 0; q < 16; ++q) Bx[g * 16 + q][c] = acc[q] + bb; }
    __syncthreads(); ln_silu(Bx, ln1s, ln1b, t); __syncthreads();
    float* Ff = &A[0][0];
    {
        float a2[16];
#pragma unroll
        for (int q = 0; q < 16; ++q) a2[q] = 0.f;
        for (int it = 0; it < HDIM / 4; ++it) {
            const float wa = W2[(4 * it + 0) * NOUT + c], wb = W2[(4 * it + 1) * NOUT + c];
            const float wc = W2[(4 * it + 2) * NOUT + c], wd = W2[(4 * it + 3) * NOUT + c];
#pragma unroll
            for (int q = 0; q < 16; ++q) {
                const float4 x4 = *reinterpret_cast<const float4*>(&Bx[g * 16 + q][4 * it]);
                a2[q] = fmaf(x4.x, wa, fmaf(x4.y, wb, fmaf(x4.z, wc, fmaf(x4.w, wd, a2[q]))));
            }
        }
        const float bb = b2[c];
#pragma unroll
        for (int q = 0; q < 16; ++q) Ff[(g * 16 + q) * NOUT + c] = (a2[q] + bb) * 0.2f;
    }
    {
        const int c2 = HDIM + (t & 31);
        const int g8 = t >> 5;
        float a2[4] = {0.f, 0.f, 0.f, 0.f};
        for (int it = 0; it < HDIM / 4; ++it) {
            const float wa = W2[(4 * it + 0) * NOUT + c2], wb = W2[(4 * it + 1) * NOUT + c2];
            const float wc = W2[(4 * it + 2) * NOUT + c2], wd = W2[(4 * it + 3) * NOUT + c2];
#pragma unroll
            for (int q = 0; q < 4; ++q) {
                const float4 x4 = *reinterpret_cast<const float4*>(&Bx[g8 * 4 + q][4 * it]);
                a2[q] = fmaf(x4.x, wa, fmaf(x4.y, wb, fmaf(x4.z, wc, fmaf(x4.w, wd, a2[q]))));
            }
        }
        const float bb = b2[c2];
#pragma unroll
        for (int q = 0; q < 4; ++q) Ff[(g8 * 4 + q) * NOUT + c2] = (a2[q] + bb) * 0.2f;
    }
    __syncthreads();
    for (int r = 0; r < EB; ++r) {
        const int e = e0 + r;
        if (e >= n_edges) break;
        const float* wrow = wigner + (size_t)e * WIG_ROW;
        float* orow = out + (size_t)rNode[r] * (NKF * 32);
        const float* Fr = Ff + r * NOUT;
#pragma unroll
        for (int jj = 0; jj < 4; ++jj) {
            const int p = t + NTHREADS * jj;
            if (p < NKF * 32) {
                const int k = p >> 5, chh = p & 31;
                float val = 0.f;
#pragma unroll
                for (int m = 0; m < 5; ++m)
                    val = fmaf(wrow[k * WIG_LD + m], Fr[m * 32 + chh], val);
                atomicAdd(&orow[p], val);
            }
        }
    }
}

// ---------------------------------------------------------------- launch
extern "C" void kernel_launch(void* const* d_in, const int* in_sizes, int n_in,
                              void* d_out, int out_size, void* d_ws, size_t ws_size,
                              hipStream_t stream)
{
    const int*   species     = (const int*)d_in[0];
    const float* edge_embeds = (const float*)d_in[1];
    const int*   senders     = (const int*)d_in[2];
    const int*   receivers   = (const int*)d_in[3];
    const float* wigner      = (const float*)d_in[4];
    const float* embed_table = (const float*)d_in[5];
    const float* W0 = (const float*)d_in[6];
    const float* b0 = (const float*)d_in[7];
    const float* ln0s = (const float*)d_in[8];
    const float* ln0b = (const float*)d_in[9];
    const float* W1 = (const float*)d_in[10];
    const float* b1 = (const float*)d_in[11];
    const float* ln1s = (const float*)d_in[12];
    const float* ln1b = (const float*)d_in[13];
    const float* W2 = (const float*)d_in[14];
    const float* b2 = (const float*)d_in[15];
    float* out = (float*)d_out;

    const int n_nodes = in_sizes[0];
    const int n_edges = in_sizes[2];

    const size_t fBytes    = (size_t)n_edges * NOUT * sizeof(float);
    const size_t offBytes  = (size_t)(n_nodes + 1) * sizeof(int);
    const size_t curBytes  = (size_t)n_nodes * sizeof(int);
    const size_t listBytes = (size_t)n_edges * sizeof(int);
    const size_t need = fBytes + offBytes + curBytes + listBytes;

    if (ws_size < need || n_nodes > SCAN_T * SCAN_CH) {
        // fallback: round-0 fused atomic kernel
        hipMemsetAsync(out, 0, (size_t)out_size * sizeof(float), stream);
        const int nblocks = (n_edges + EB - 1) / EB;
        hipLaunchKernelGGL(edge_fused_kernel, dim3(nblocks), dim3(NTHREADS), 0, stream,
                           species, edge_embeds, senders, receivers, wigner, embed_table,
                           W0, b0, ln0s, ln0b, W1, b1, ln1s, ln1b, W2, b2, out, n_edges);
        return;
    }

    char* ws = (char*)d_ws;
    float* F       = (float*)ws;
    int*   offsets = (int*)(ws + fBytes);
    int*   cursor  = (int*)(ws + fBytes + offBytes);
    int*   elist   = (int*)(ws + fBytes + offBytes + curBytes);

    const int egrid = (n_edges + 255) / 256;

    // CSR build: cnt (in cursor buf) -> offsets -> cursor -> elist
    hipMemsetAsync(cursor, 0, curBytes, stream);
    hipLaunchKernelGGL(hist_kernel, dim3(egrid), dim3(256), 0, stream,
                       receivers, cursor, n_edges);
    hipLaunchKernelGGL(scan_kernel, dim3(1), dim3(SCAN_T), 0, stream,
                       cursor, offsets, n_nodes);
    hipMemcpyAsync(cursor, offsets, curBytes, hipMemcpyDeviceToDevice, stream);
    hipLaunchKernelGGL(scatter_kernel, dim3(egrid), dim3(256), 0, stream,
                       receivers, cursor, elist, n_edges);

    // MLP -> F
    const int mblocks = (n_edges + EB - 1) / EB;
    hipLaunchKernelGGL(mlp_kernel, dim3(mblocks), dim3(NTHREADS), 0, stream,
                       species, edge_embeds, senders, receivers, embed_table,
                       W0, b0, ln0s, ln0b, W1, b1, ln1s, ln1b, W2, b2, F, n_edges);

    // gather-aggregate -> out (writes every node, no memset needed)
    hipLaunchKernelGGL(agg_kernel, dim3(n_nodes), dim3(256), 0, stream,
                       wigner, F, offsets, elist, out);
}

// Round 3
// 607.169 us; speedup vs baseline: 4.7108x; 2.1895x over previous
//
#include <hip/hip_runtime.h>
#include <cstddef>

// EdgeDegreeEmbedding, round 2: MFMA bf16 MLP (hi/lo W split), CSR gather agg.
//
//  repack_w : W0/W1/W2 f32 -> bf16 hi+lo fragments in MFMA B-layout (ws, 344 KB)
//  mlp_mfma : 128 edges/block, 512 thr (8 waves). Per GEMM: wave w owns N-tile w,
//             8 M-tiles, K-loop with 2 MFMA terms (Wh, Wl) per A-frag.
//             LN+silu in f32 LDS between layers. F[E,160] f32 -> ws.
//  CSR build + agg_kernel: unchanged from round 1.

#define MB 128
#define MTHREADS 512
#define DIN 384
#define HDIM 128
#define NOUT 160
#define NKF 25
#define WIG_LD 19
#define WIG_ROW 475

// LDS layout (bytes)
#define XS_B   784      // Xb row stride: (384+8) bf16
#define FS_B   528      // H0f/H1f row stride: 132 f32
#define HS_B   272      // H0b/H1b row stride: (128+8) bf16
#define REG0   0        // Xb (100352 B) / H0f,H1f (67584 B)
#define REG1   100352   // H0b/H1b (34816 B)
#define METAS  135168   // sS[128]
#define METAR  135680   // rS[128]
#define LDSSZ  136192

typedef __attribute__((ext_vector_type(8))) short short8;
typedef __attribute__((ext_vector_type(4))) float f32x4;

__device__ __forceinline__ unsigned short f2bf(float f)
{
    union { float f; unsigned u; } x; x.f = f;
    unsigned r = x.u + 0x7fffu + ((x.u >> 16) & 1u);
    return (unsigned short)(r >> 16);
}

// ---------------------------------------------------------------- W repack
// Wp fragment block (1024 B) = one (kt, nt, term): 64 lanes x 8 bf16.
// lane l holds B[kt*32 + 8*(l>>4)+i][nt*16 + (l&15)].
__global__ void repack_w(const float* __restrict__ W0, const float* __restrict__ W1,
                         const float* __restrict__ W2, unsigned short* __restrict__ Wp)
{
    const int id = blockIdx.x * 256 + threadIdx.x;
    const float* W; int k, n, NT, N; size_t base;  // base in ushort units
    if (id < 49152)      { W = W0; k = id >> 7;  n = id & 127;  NT = 8;  N = 128; base = 0; }
    else if (id < 65536) { int r = id - 49152; W = W1; k = r >> 7; n = r & 127; NT = 8; N = 128; base = 98304; }
    else if (id < 86016) { int r = id - 65536; W = W2; k = r / 160; n = r - 160 * k; NT = 10; N = 160; base = 131072; }
    else return;
    const float w = W[(size_t)k * N + n];
    const unsigned short hi = f2bf(w);
    union { unsigned u; float f; } hf; hf.u = ((unsigned)hi) << 16;
    const unsigned short lo = f2bf(w - hf.f);
    const int kt = k >> 5, kk = k & 31;
    const int l = ((kk >> 3) << 4) | (n & 15);
    const int i = kk & 7;
    const int nt = n >> 4;
    const size_t o = base + (size_t)((kt * NT + nt) * 2) * 512 + l * 8 + i;
    Wp[o] = hi;
    Wp[o + 512] = lo;
}

// ---------------------------------------------------------------- GEMM core
__device__ __forceinline__ void gemm_tiles(const char* __restrict__ ldsA, int astride,
                                           const char* __restrict__ wp, int NT, int KT,
                                           int nt, int lane, f32x4 acc[8])
{
    const int lr = lane & 15, lk = lane >> 4;
    for (int kt = 0; kt < KT; ++kt) {
        const char* wb = wp + (size_t)((kt * NT + nt) * 2) * 1024 + lane * 16;
        const short8 bh = *(const short8*)(wb);
        const short8 bl = *(const short8*)(wb + 1024);
        short8 a[8];
#pragma unroll
        for (int mt = 0; mt < 8; ++mt)
            a[mt] = *(const short8*)(ldsA + (mt * 16 + lr) * astride + kt * 64 + lk * 16);
#pragma unroll
        for (int mt = 0; mt < 8; ++mt) {
            acc[mt] = __builtin_amdgcn_mfma_f32_16x16x32_bf16(a[mt], bh, acc[mt], 0, 0, 0);
            acc[mt] = __builtin_amdgcn_mfma_f32_16x16x32_bf16(a[mt], bl, acc[mt], 0, 0, 0);
        }
    }
}

__device__ __forceinline__ void dump_acc(char* Hf, int nt, int lane, const f32x4 acc[8],
                                         const float bias)
{
    const int lr = lane & 15, lk = lane >> 4;
#pragma unroll
    for (int mt = 0; mt < 8; ++mt)
#pragma unroll
        for (int i = 0; i < 4; ++i)
            *(float*)(Hf + (mt * 16 + lk * 4 + i) * FS_B + (nt * 16 + lr) * 4) = acc[mt][i] + bias;
}

// LN + silu: read f32 (stride FS_B), write packed bf16 (stride HS_B).
__device__ __forceinline__ void ln_silu_bf(const char* Hf, char* Hb,
                                           const float* __restrict__ s,
                                           const float* __restrict__ b, int t)
{
    const int j = t & 7;
#pragma unroll
    for (int half = 0; half < 2; ++half) {
        const int r = (t >> 3) + 64 * half;
        float v[16];
        float sum = 0.f, sq = 0.f;
#pragma unroll
        for (int q = 0; q < 16; ++q) {
            v[q] = *(const float*)(Hf + r * FS_B + (j * 16 + q) * 4);
            sum += v[q];
            sq = fmaf(v[q], v[q], sq);
        }
#pragma unroll
        for (int m = 1; m < 8; m <<= 1) {
            sum += __shfl_xor(sum, m, 64);
            sq  += __shfl_xor(sq,  m, 64);
        }
        const float mu = sum * (1.f / 128.f);
        const float var = sq * (1.f / 128.f) - mu * mu;
        const float rstd = rsqrtf(var + 1e-6f);
#pragma unroll
        for (int q = 0; q < 16; q += 2) {
            const int c0 = j * 16 + q;
            float y0 = (v[q] - mu) * rstd * s[c0] + b[c0];
            float y1 = (v[q + 1] - mu) * rstd * s[c0 + 1] + b[c0 + 1];
            y0 = y0 / (1.f + __expf(-y0));
            y1 = y1 / (1.f + __expf(-y1));
            const unsigned pk = (unsigned)f2bf(y0) | ((unsigned)f2bf(y1) << 16);
            *(unsigned*)(Hb + r * HS_B + c0 * 2) = pk;
        }
    }
}

// ---------------------------------------------------------------- MLP (MFMA)
__global__ __launch_bounds__(MTHREADS, 1)
void mlp_mfma(
    const int* __restrict__ species,
    const float* __restrict__ edge_embeds,
    const int* __restrict__ senders,
    const int* __restrict__ receivers,
    const float* __restrict__ embed_table,
    const char* __restrict__ Wp,
    const float* __restrict__ b0, const float* __restrict__ ln0s, const float* __restrict__ ln0b,
    const float* __restrict__ b1, const float* __restrict__ ln1s, const float* __restrict__ ln1b,
    const float* __restrict__ b2,
    float* __restrict__ F,
    int n_edges)
{
    __shared__ alignas(16) char lds[LDSSZ];
    int* sS = (int*)(lds + METAS);
    int* rS = (int*)(lds + METAR);

    const int t = threadIdx.x;
    const int e0 = blockIdx.x * MB;
    const int w = t >> 6;
    const int lane = t & 63;
    const int lr = lane & 15, lk = lane >> 4;

    if (t < MB) {
        const int e = e0 + t;
        int s = 0, r = 0;
        if (e < n_edges) { s = senders[e]; r = receivers[e]; }
        sS[t] = species[s];
        rS[t] = species[r];
    }
    __syncthreads();

    // ---- stage X -> bf16 LDS ----
    {
        const int row = t >> 2;
        const int e = e0 + row;
        const bool ev = e < n_edges;
        const int ss = sS[row], rr = rS[row];
        char* xrow = lds + REG0 + row * XS_B;
        const int cbase = 4 * (t & 3);
#pragma unroll
        for (int jj = 0; jj < 8; ++jj) {          // cols 0..127: edge_embeds
            const int col = cbase + 16 * jj;
            float4 v = make_float4(0.f, 0.f, 0.f, 0.f);
            if (ev) v = *(const float4*)(edge_embeds + (size_t)e * 128 + col);
            ushort4 pk = {f2bf(v.x), f2bf(v.y), f2bf(v.z), f2bf(v.w)};
            *(ushort4*)(xrow + col * 2) = pk;
        }
#pragma unroll
        for (int jj = 8; jj < 16; ++jj) {         // cols 128..255: sender emb
            const int col = cbase + 16 * jj;
            float4 v = make_float4(0.f, 0.f, 0.f, 0.f);
            if (ev) v = *(const float4*)(embed_table + (size_t)ss * 256 + (col - 128));
            ushort4 pk = {f2bf(v.x), f2bf(v.y), f2bf(v.z), f2bf(v.w)};
            *(ushort4*)(xrow + col * 2) = pk;
        }
#pragma unroll
        for (int jj = 16; jj < 24; ++jj) {        // cols 256..383: receiver emb
            const int col = cbase + 16 * jj;
            float4 v = make_float4(0.f, 0.f, 0.f, 0.f);
            if (ev) v = *(const float4*)(embed_table + (size_t)rr * 256 + 128 + (col - 256));
            ushort4 pk = {f2bf(v.x), f2bf(v.y), f2bf(v.z), f2bf(v.w)};
            *(ushort4*)(xrow + col * 2) = pk;
        }
    }
    __syncthreads();

    const char* wp0 = Wp;
    const char* wp1 = Wp + 196608;
    const char* wp2 = Wp + 262144;

    f32x4 acc[8];

    // ---- GEMM1: X[128,384] @ W0 -> H0 ----
#pragma unroll
    for (int mt = 0; mt < 8; ++mt) acc[mt] = (f32x4){0.f, 0.f, 0.f, 0.f};
    gemm_tiles(lds + REG0, XS_B, wp0, 8, 12, w, lane, acc);
    __syncthreads();                       // Xb dead; reuse REG0 as H0f
    dump_acc(lds + REG0, w, lane, acc, b0[w * 16 + lr]);
    __syncthreads();
    ln_silu_bf(lds + REG0, lds + REG1, ln0s, ln0b, t);   // H0f -> H0b
    __syncthreads();

    // ---- GEMM2: H0[128,128] @ W1 -> H1 ----
#pragma unroll
    for (int mt = 0; mt < 8; ++mt) acc[mt] = (f32x4){0.f, 0.f, 0.f, 0.f};
    gemm_tiles(lds + REG1, HS_B, wp1, 8, 4, w, lane, acc);
    __syncthreads();                       // H0f dead; reuse REG0 as H1f
    dump_acc(lds + REG0, w, lane, acc, b1[w * 16 + lr]);
    __syncthreads();
    ln_silu_bf(lds + REG0, lds + REG1, ln1s, ln1b, t);   // H1f -> H1b (H0b dead)
    __syncthreads();

    // ---- GEMM3: H1[128,128] @ W2 -> F (x0.2), direct global stores ----
#pragma unroll
    for (int p = 0; p < 2; ++p) {
        const int nt = w + 8 * p;
        if (nt >= 10) break;
#pragma unroll
        for (int mt = 0; mt < 8; ++mt) acc[mt] = (f32x4){0.f, 0.f, 0.f, 0.f};
        gemm_tiles(lds + REG1, HS_B, wp2, 10, 4, nt, lane, acc);
        const float bb = b2[nt * 16 + lr];
#pragma unroll
        for (int mt = 0; mt < 8; ++mt)
#pragma unroll
            for (int i = 0; i < 4; ++i) {
                const int e = e0 + mt * 16 + lk * 4 + i;
                if (e < n_edges)
                    F[(size_t)e * NOUT + nt * 16 + lr] = (acc[mt][i] + bb) * 0.2f;
            }
    }
}

// ---------------------------------------------------------------- CSR build
__global__ void hist_kernel(const int* __restrict__ recv, int* __restrict__ cnt, int n_edges)
{
    const int e = blockIdx.x * 256 + threadIdx.x;
    if (e < n_edges) atomicAdd(&cnt[recv[e]], 1);
}

#define SCAN_T 1024
#define SCAN_CH 20
__global__ __launch_bounds__(SCAN_T)
void scan_kernel(const int* __restrict__ cnt, int* __restrict__ offsets, int n_nodes)
{
    __shared__ int waveSum[SCAN_T / 64];
    const int t = threadIdx.x;
    const int base = t * SCAN_CH;
    int local[SCAN_CH];
    int s = 0;
#pragma unroll
    for (int j = 0; j < SCAN_CH; ++j) {
        const int v = (base + j < n_nodes) ? cnt[base + j] : 0;
        local[j] = s;
        s += v;
    }
    const int lane = t & 63;
    int incl = s;
#pragma unroll
    for (int d = 1; d < 64; d <<= 1) {
        const int u = __shfl_up(incl, d, 64);
        if (lane >= d) incl += u;
    }
    if (lane == 63) waveSum[t >> 6] = incl;
    __syncthreads();
    if (t < SCAN_T / 64) {
        const int v = waveSum[t];
        int incl2 = v;
#pragma unroll
        for (int d = 1; d < SCAN_T / 64; d <<= 1) {
            const int u = __shfl_up(incl2, d, 64);
            if (lane >= d) incl2 += u;
        }
        waveSum[t] = incl2 - v;
    }
    __syncthreads();
    const int threadExcl = waveSum[t >> 6] + (incl - s);
#pragma unroll
    for (int j = 0; j < SCAN_CH; ++j)
        if (base + j < n_nodes) offsets[base + j] = threadExcl + local[j];
    if (t == SCAN_T - 1) offsets[n_nodes] = threadExcl + s;
}

__global__ void scatter_kernel(const int* __restrict__ recv, int* __restrict__ cursor,
                               int* __restrict__ elist, int n_edges)
{
    const int e = blockIdx.x * 256 + threadIdx.x;
    if (e < n_edges) {
        const int p = atomicAdd(&cursor[recv[e]], 1);
        elist[p] = e;
    }
}

// ---------------------------------------------------------------- aggregation
__global__ __launch_bounds__(256)
void agg_kernel(const float* __restrict__ wigner, const float* __restrict__ F,
                const int* __restrict__ offsets, const int* __restrict__ elist,
                float* __restrict__ out)
{
    const int n = blockIdx.x;
    const int t = threadIdx.x;
    __shared__ float wigS[2][128];
    __shared__ float Fe[2][NOUT];

    const int beg = offsets[n];
    const int end = offsets[n + 1];

    const int ch = t & 31;
    const int k0 = t >> 5;
    float acc0 = 0.f, acc1 = 0.f, acc2 = 0.f, acc3 = 0.f;

    if (beg < end) {
        const int e = elist[beg];
        if (t < 125) wigS[0][t] = wigner[(size_t)e * WIG_ROW + (t / 5) * WIG_LD + (t % 5)];
        if (t >= 128 && t < 168)
            *reinterpret_cast<float4*>(&Fe[0][4 * (t - 128)]) =
                *reinterpret_cast<const float4*>(&F[(size_t)e * NOUT + 4 * (t - 128)]);
    }

    int buf = 0;
    for (int i = beg; i < end; ++i) {
        __syncthreads();
        if (i + 1 < end) {
            const int e = elist[i + 1];
            if (t < 125) wigS[buf ^ 1][t] = wigner[(size_t)e * WIG_ROW + (t / 5) * WIG_LD + (t % 5)];
            if (t >= 128 && t < 168)
                *reinterpret_cast<float4*>(&Fe[buf ^ 1][4 * (t - 128)]) =
                    *reinterpret_cast<const float4*>(&F[(size_t)e * NOUT + 4 * (t - 128)]);
        }
        const float f0 = Fe[buf][ch];
        const float f1 = Fe[buf][32 + ch];
        const float f2 = Fe[buf][64 + ch];
        const float f3 = Fe[buf][96 + ch];
        const float f4 = Fe[buf][128 + ch];
        const float* wp = &wigS[buf][0];
        { const float* wq = wp + k0 * 5;        acc0 += wq[0]*f0 + wq[1]*f1 + wq[2]*f2 + wq[3]*f3 + wq[4]*f4; }
        { const float* wq = wp + (k0 + 8) * 5;  acc1 += wq[0]*f0 + wq[1]*f1 + wq[2]*f2 + wq[3]*f3 + wq[4]*f4; }
        { const float* wq = wp + (k0 + 16) * 5; acc2 += wq[0]*f0 + wq[1]*f1 + wq[2]*f2 + wq[3]*f3 + wq[4]*f4; }
        if (t < 32) { const float* wq = wp + 24 * 5; acc3 += wq[0]*f0 + wq[1]*f1 + wq[2]*f2 + wq[3]*f3 + wq[4]*f4; }
        buf ^= 1;
    }

    float* orow = out + (size_t)n * (NKF * 32);
    orow[t] = acc0;
    orow[t + 256] = acc1;
    orow[t + 512] = acc2;
    if (t < 32) orow[t + 768] = acc3;
}

// ---------------------------------------------------------------- fallback (round-0)
#define EB 32
__device__ __forceinline__ void ln_silu_f(float (*Bx)[HDIM], const float* __restrict__ s,
                                          const float* __restrict__ b, int t)
{
    const int r = t >> 3;
    const int j = t & 7;
    float v[16];
    float sum = 0.f, sq = 0.f;
#pragma unroll
    for (int q = 0; q < 16; ++q) { v[q] = Bx[r][j*16+q]; sum += v[q]; sq = fmaf(v[q], v[q], sq); }
#pragma unroll
    for (int m = 1; m < 8; m <<= 1) { sum += __shfl_xor(sum, m, 64); sq += __shfl_xor(sq, m, 64); }
    const float mu = sum * (1.f/HDIM);
    const float var = sq * (1.f/HDIM) - mu*mu;
    const float rstd = rsqrtf(var + 1e-6f);
#pragma unroll
    for (int q = 0; q < 16; ++q) {
        const int cc = j*16+q;
        const float y = (v[q]-mu)*rstd*s[cc]+b[cc];
        Bx[r][cc] = y / (1.f + __expf(-y));
    }
}

__global__ __launch_bounds__(256, 2)
void edge_fused_kernel(
    const int* __restrict__ species, const float* __restrict__ edge_embeds,
    const int* __restrict__ senders, const int* __restrict__ receivers,
    const float* __restrict__ wigner, const float* __restrict__ embed_table,
    const float* __restrict__ W0, const float* __restrict__ b0,
    const float* __restrict__ ln0s, const float* __restrict__ ln0b,
    const float* __restrict__ W1, const float* __restrict__ b1,
    const float* __restrict__ ln1s, const float* __restrict__ ln1b,
    const float* __restrict__ W2, const float* __restrict__ b2,
    float* __restrict__ out, int n_edges)
{
    __shared__ float A[EB][DIN];
    __shared__ float Bx[EB][HDIM];
    __shared__ int sSpec[EB], rSpec[EB], rNode[EB];
    const int t = threadIdx.x;
    const int e0 = blockIdx.x * EB;
    if (t < EB) {
        const int e = e0 + t;
        int s = 0, r = 0;
        if (e < n_edges) { s = senders[e]; r = receivers[e]; }
        sSpec[t] = species[s]; rSpec[t] = species[r]; rNode[t] = r;
    }
    __syncthreads();
    for (int idx = t; idx < EB * DIN; idx += 256) {
        const int r = idx / DIN;
        const int i = idx - r * DIN;
        const int e = e0 + r;
        float v = 0.f;
        if (e < n_edges) {
            if (i < HDIM) v = edge_embeds[(size_t)e * HDIM + i];
            else if (i < 2*HDIM) v = embed_table[(size_t)sSpec[r]*256 + (i-HDIM)];
            else v = embed_table[(size_t)rSpec[r]*256 + HDIM + (i-2*HDIM)];
        }
        A[r][i] = v;
    }
    __syncthreads();
    const int c = t & (HDIM-1);
    const int g = t >> 7;
    float acc[16];
#pragma unroll
    for (int q = 0; q < 16; ++q) acc[q] = 0.f;
    for (int it = 0; it < DIN/4; ++it) {
        const float wa = W0[(4*it+0)*HDIM+c], wb = W0[(4*it+1)*HDIM+c];
        const float wc = W0[(4*it+2)*HDIM+c], wd = W0[(4*it+3)*HDIM+c];
#pragma unroll
        for (int q = 0; q < 16; ++q) {
            const float4 x4 = *reinterpret_cast<const float4*>(&A[g*16+q][4*it]);
            acc[q] = fmaf(x4.x, wa, fmaf(x4.y, wb, fmaf(x4.z, wc, fmaf(x4.w, wd, acc[q]))));
        }
    }
    { const float bb = b0[c];
#pragma unroll
      for (int q = 0; q < 16; ++q) Bx[g*16+q][c] = acc[q] + bb; }
    __syncthreads(); ln_silu_f(Bx, ln0s, ln0b, t); __syncthreads();
#pragma unroll
    for (int q = 0; q < 16; ++q) acc[q] = 0.f;
    for (int it = 0; it < HDIM/4; ++it) {
        const float wa = W1[(4*it+0)*HDIM+c], wb = W1[(4*it+1)*HDIM+c];
        const float wc = W1[(4*it+2)*HDIM+c], wd = W1[(4*it+3)*HDIM+c];
#pragma unroll
        for (int q = 0; q < 16; ++q) {
            const float4 x4 = *reinterpret_cast<const float4*>(&Bx[g*16+q][4*it]);
            acc[q] = fmaf(x4.x, wa, fmaf(x4.y, wb, fmaf(x4.z, wc, fmaf(x4.w, wd, acc[q]))));
        }
    }
    __syncthreads();
    { const float bb = b1[c];
#pragma unroll
      for (int q = 0; q < 16; ++q) Bx[g*16+q][c] = acc[q] + bb; }
    __syncthreads(); ln_silu_f(Bx, ln1s, ln1b, t); __syncthreads();
    float* Ff = &A[0][0];
    {
        float a2[16];
#pragma unroll
        for (int q = 0; q < 16; ++q) a2[q] = 0.f;
        for (int it = 0; it < HDIM/4; ++it) {
            const float wa = W2[(4*it+0)*NOUT+c], wb = W2[(4*it+1)*NOUT+c];
            const float wc = W2[(4*it+2)*NOUT+c], wd = W2[(4*it+3)*NOUT+c];
#pragma unroll
            for (int q = 0; q < 16; ++q) {
                const float4 x4 = *reinterpret_cast<const float4*>(&Bx[g*16+q][4*it]);
                a2[q] = fmaf(x4.x, wa, fmaf(x4.y, wb, fmaf(x4.z, wc, fmaf(x4.w, wd, a2[q]))));
            }
        }
        const float bb = b2[c];
#pragma unroll
        for (int q = 0; q < 16; ++q) Ff[(g*16+q)*NOUT+c] = (a2[q]+bb)*0.2f;
    }
    {
        const int c2 = HDIM + (t & 31);
        const int g8 = t >> 5;
        float a2[4] = {0.f, 0.f, 0.f, 0.f};
        for (int it = 0; it < HDIM/4; ++it) {
            const float wa = W2[(4*it+0)*NOUT+c2], wb = W2[(4*it+1)*NOUT+c2];
            const float wc = W2[(4*it+2)*NOUT+c2], wd = W2[(4*it+3)*NOUT+c2];
#pragma unroll
            for (int q = 0; q < 4; ++q) {
                const float4 x4 = *reinterpret_cast<const float4*>(&Bx[g8*4+q][4*it]);
                a2[q] = fmaf(x4.x, wa, fmaf(x4.y, wb, fmaf(x4.z, wc, fmaf(x4.w, wd, a2[q]))));
            }
        }
        const float bb = b2[c2];
#pragma unroll
        for (int q = 0; q < 4; ++q) Ff[(g8*4+q)*NOUT+c2] = (a2[q]+bb)*0.2f;
    }
    __syncthreads();
    for (int r = 0; r < EB; ++r) {
        const int e = e0 + r;
        if (e >= n_edges) break;
        const float* wrow = wigner + (size_t)e * WIG_ROW;
        float* orow = out + (size_t)rNode[r] * (NKF*32);
        const float* Fr = Ff + r * NOUT;
#pragma unroll
        for (int jj = 0; jj < 4; ++jj) {
            const int p = t + 256*jj;
            if (p < NKF*32) {
                const int k = p >> 5, chh = p & 31;
                float val = 0.f;
#pragma unroll
                for (int m = 0; m < 5; ++m)
                    val = fmaf(wrow[k*WIG_LD+m], Fr[m*32+chh], val);
                atomicAdd(&orow[p], val);
            }
        }
    }
}

// ---------------------------------------------------------------- launch
extern "C" void kernel_launch(void* const* d_in, const int* in_sizes, int n_in,
                              void* d_out, int out_size, void* d_ws, size_t ws_size,
                              hipStream_t stream)
{
    const int*   species     = (const int*)d_in[0];
    const float* edge_embeds = (const float*)d_in[1];
    const int*   senders     = (const int*)d_in[2];
    const int*   receivers   = (const int*)d_in[3];
    const float* wigner      = (const float*)d_in[4];
    const float* embed_table = (const float*)d_in[5];
    const float* W0 = (const float*)d_in[6];
    const float* b0 = (const float*)d_in[7];
    const float* ln0s = (const float*)d_in[8];
    const float* ln0b = (const float*)d_in[9];
    const float* W1 = (const float*)d_in[10];
    const float* b1 = (const float*)d_in[11];
    const float* ln1s = (const float*)d_in[12];
    const float* ln1b = (const float*)d_in[13];
    const float* W2 = (const float*)d_in[14];
    const float* b2 = (const float*)d_in[15];
    float* out = (float*)d_out;

    const int n_nodes = in_sizes[0];
    const int n_edges = in_sizes[2];

    const size_t wpBytes   = 344064;
    const size_t fBytes    = (size_t)n_edges * NOUT * sizeof(float);
    const size_t offBytes  = (size_t)(n_nodes + 1) * sizeof(int);
    const size_t curBytes  = (size_t)n_nodes * sizeof(int);
    const size_t listBytes = (size_t)n_edges * sizeof(int);
    const size_t need = wpBytes + fBytes + offBytes + curBytes + listBytes + 64;

    if (ws_size < need || n_nodes > SCAN_T * SCAN_CH) {
        hipMemsetAsync(out, 0, (size_t)out_size * sizeof(float), stream);
        const int nblocks = (n_edges + EB - 1) / EB;
        hipLaunchKernelGGL(edge_fused_kernel, dim3(nblocks), dim3(256), 0, stream,
                           species, edge_embeds, senders, receivers, wigner, embed_table,
                           W0, b0, ln0s, ln0b, W1, b1, ln1s, ln1b, W2, b2, out, n_edges);
        return;
    }

    char* ws = (char*)d_ws;
    unsigned short* Wp = (unsigned short*)ws;
    float* F       = (float*)(ws + wpBytes);
    int*   offsets = (int*)(ws + wpBytes + fBytes);
    int*   cursor  = (int*)(ws + wpBytes + fBytes + offBytes);
    int*   elist   = (int*)(ws + wpBytes + fBytes + offBytes + curBytes);

    const int egrid = (n_edges + 255) / 256;

    // weight repack (tiny; L2-resident afterwards)
    hipLaunchKernelGGL(repack_w, dim3(336), dim3(256), 0, stream, W0, W1, W2, Wp);

    // CSR build
    hipMemsetAsync(cursor, 0, curBytes, stream);
    hipLaunchKernelGGL(hist_kernel, dim3(egrid), dim3(256), 0, stream,
                       receivers, cursor, n_edges);
    hipLaunchKernelGGL(scan_kernel, dim3(1), dim3(SCAN_T), 0, stream,
                       cursor, offsets, n_nodes);
    hipMemcpyAsync(cursor, offsets, curBytes, hipMemcpyDeviceToDevice, stream);
    hipLaunchKernelGGL(scatter_kernel, dim3(egrid), dim3(256), 0, stream,
                       receivers, cursor, elist, n_edges);

    // MLP (MFMA) -> F
    const int mblocks = (n_edges + MB - 1) / MB;
    hipLaunchKernelGGL(mlp_mfma, dim3(mblocks), dim3(MTHREADS), 0, stream,
                       species, edge_embeds, senders, receivers, embed_table,
                       (const char*)Wp, b0, ln0s, ln0b, b1, ln1s, ln1b, b2, F, n_edges);

    // gather-aggregate -> out
    hipLaunchKernelGGL(agg_kernel, dim3(n_nodes), dim3(256), 0, stream,
                       wigner, F, offsets, elist, out);
}

// Round 4
// 527.470 us; speedup vs baseline: 5.4226x; 1.1511x over previous
//
#include <hip/hip_runtime.h>
#include <hip/hip_bf16.h>
#include <cstddef>

// EdgeDegreeEmbedding, round 3.
//  - mlp_mfma: MB=64 edges/block (LDS 68KB -> 2 blocks/CU, was 1), packed
//    f32->bf16 cvt for staging/LN, one barrier removed (GEMM2->dump).
//  - agg_kernel: F prefetched into registers (no LDS stage), wigner
//    double-buffered in LDS.
//  - CSR build unchanged; round-0 fallback retained.

#define MB 64
#define MTHREADS 512
#define DIN 384
#define HDIM 128
#define NOUT 160
#define NKF 25
#define WIG_LD 19
#define WIG_ROW 475

// LDS layout (bytes)
#define XS_B   784      // Xb row stride: (384+8) bf16
#define FS_B   528      // H0f/H1f row stride: 132 f32
#define HS_B   272      // H0b/H1b row stride: (128+8) bf16
#define REG0   0        // Xb (64*784=50176) / H0f,H1f (64*528=33792)
#define REG1   50176    // H0b/H1b (64*272=17408)
#define METAS  67584    // sS[64]
#define METAR  67840    // rS[64]
#define LDSSZ  68096

typedef __attribute__((ext_vector_type(8))) short short8;
typedef __attribute__((ext_vector_type(4))) float f32x4;

struct BF4 { __hip_bfloat162 a, b; };   // 8 B = 4 bf16

__device__ __forceinline__ unsigned short f2bf(float f)
{
    union { float f; unsigned u; } x; x.f = f;
    unsigned r = x.u + 0x7fffu + ((x.u >> 16) & 1u);
    return (unsigned short)(r >> 16);
}

// ---------------------------------------------------------------- W repack
// Wp fragment block (1024 B) = one (kt, nt, term): 64 lanes x 8 bf16.
// lane l holds B[kt*32 + 8*(l>>4)+i][nt*16 + (l&15)].
__global__ void repack_w(const float* __restrict__ W0, const float* __restrict__ W1,
                         const float* __restrict__ W2, unsigned short* __restrict__ Wp)
{
    const int id = blockIdx.x * 256 + threadIdx.x;
    const float* W; int k, n, NT, N; size_t base;  // base in ushort units
    if (id < 49152)      { W = W0; k = id >> 7;  n = id & 127;  NT = 8;  N = 128; base = 0; }
    else if (id < 65536) { int r = id - 49152; W = W1; k = r >> 7; n = r & 127; NT = 8; N = 128; base = 98304; }
    else if (id < 86016) { int r = id - 65536; W = W2; k = r / 160; n = r - 160 * k; NT = 10; N = 160; base = 131072; }
    else return;
    const float w = W[(size_t)k * N + n];
    const unsigned short hi = f2bf(w);
    union { unsigned u; float f; } hf; hf.u = ((unsigned)hi) << 16;
    const unsigned short lo = f2bf(w - hf.f);
    const int kt = k >> 5, kk = k & 31;
    const int l = ((kk >> 3) << 4) | (n & 15);
    const int i = kk & 7;
    const int nt = n >> 4;
    const size_t o = base + (size_t)((kt * NT + nt) * 2) * 512 + l * 8 + i;
    Wp[o] = hi;
    Wp[o + 512] = lo;
}

// ---------------------------------------------------------------- GEMM core
// 4 M-tiles (64 rows) per wave, N-tile nt, K-tiles KT, hi+lo terms.
__device__ __forceinline__ void gemm_tiles(const char* __restrict__ ldsA, int astride,
                                           const char* __restrict__ wp, int NT, int KT,
                                           int nt, int lane, f32x4 acc[4])
{
    const int lr = lane & 15, lk = lane >> 4;
    for (int kt = 0; kt < KT; ++kt) {
        const char* wb = wp + (size_t)((kt * NT + nt) * 2) * 1024 + lane * 16;
        const short8 bh = *(const short8*)(wb);
        const short8 bl = *(const short8*)(wb + 1024);
        short8 a[4];
#pragma unroll
        for (int mt = 0; mt < 4; ++mt)
            a[mt] = *(const short8*)(ldsA + (mt * 16 + lr) * astride + kt * 64 + lk * 16);
#pragma unroll
        for (int mt = 0; mt < 4; ++mt) {
            acc[mt] = __builtin_amdgcn_mfma_f32_16x16x32_bf16(a[mt], bh, acc[mt], 0, 0, 0);
            acc[mt] = __builtin_amdgcn_mfma_f32_16x16x32_bf16(a[mt], bl, acc[mt], 0, 0, 0);
        }
    }
}

__device__ __forceinline__ void dump_acc(char* Hf, int nt, int lane, const f32x4 acc[4],
                                         const float bias)
{
    const int lr = lane & 15, lk = lane >> 4;
#pragma unroll
    for (int mt = 0; mt < 4; ++mt)
#pragma unroll
        for (int i = 0; i < 4; ++i)
            *(float*)(Hf + (mt * 16 + lk * 4 + i) * FS_B + (nt * 16 + lr) * 4) = acc[mt][i] + bias;
}

// LN + silu: read f32 (stride FS_B), write packed bf16 (stride HS_B).
// 512 threads, 64 rows, 8 threads/row x 16 channels.
__device__ __forceinline__ void ln_silu_bf(const char* Hf, char* Hb,
                                           const float* __restrict__ s,
                                           const float* __restrict__ b, int t)
{
    const int j = t & 7;
    const int r = t >> 3;
    float v[16];
    float sum = 0.f, sq = 0.f;
#pragma unroll
    for (int q4 = 0; q4 < 4; ++q4) {
        const float4 x4 = *(const float4*)(Hf + r * FS_B + (j * 16 + q4 * 4) * 4);
        v[q4 * 4 + 0] = x4.x; v[q4 * 4 + 1] = x4.y;
        v[q4 * 4 + 2] = x4.z; v[q4 * 4 + 3] = x4.w;
    }
#pragma unroll
    for (int q = 0; q < 16; ++q) { sum += v[q]; sq = fmaf(v[q], v[q], sq); }
#pragma unroll
    for (int m = 1; m < 8; m <<= 1) {
        sum += __shfl_xor(sum, m, 64);
        sq  += __shfl_xor(sq,  m, 64);
    }
    const float mu = sum * (1.f / 128.f);
    const float var = sq * (1.f / 128.f) - mu * mu;
    const float rstd = rsqrtf(var + 1e-6f);
#pragma unroll
    for (int q = 0; q < 16; q += 2) {
        const int c0 = j * 16 + q;
        float y0 = (v[q] - mu) * rstd * s[c0] + b[c0];
        float y1 = (v[q + 1] - mu) * rstd * s[c0 + 1] + b[c0 + 1];
        y0 = y0 / (1.f + __expf(-y0));
        y1 = y1 / (1.f + __expf(-y1));
        *(__hip_bfloat162*)(Hb + r * HS_B + c0 * 2) =
            __float22bfloat162_rn(make_float2(y0, y1));
    }
}

// ---------------------------------------------------------------- MLP (MFMA)
__global__ __launch_bounds__(MTHREADS, 4)
void mlp_mfma(
    const int* __restrict__ species,
    const float* __restrict__ edge_embeds,
    const int* __restrict__ senders,
    const int* __restrict__ receivers,
    const float* __restrict__ embed_table,
    const char* __restrict__ Wp,
    const float* __restrict__ b0, const float* __restrict__ ln0s, const float* __restrict__ ln0b,
    const float* __restrict__ b1, const float* __restrict__ ln1s, const float* __restrict__ ln1b,
    const float* __restrict__ b2,
    float* __restrict__ F,
    int n_edges)
{
    __shared__ alignas(16) char lds[LDSSZ];
    int* sS = (int*)(lds + METAS);
    int* rS = (int*)(lds + METAR);

    const int t = threadIdx.x;
    const int e0 = blockIdx.x * MB;
    const int w = t >> 6;
    const int lane = t & 63;
    const int lr = lane & 15, lk = lane >> 4;

    if (t < MB) {
        const int e = e0 + t;
        int s = 0, r = 0;
        if (e < n_edges) { s = senders[e]; r = receivers[e]; }
        sS[t] = species[s];
        rS[t] = species[r];
    }
    __syncthreads();

    // ---- stage X -> bf16 LDS (8 threads/row, 4-col chunks, stride 32) ----
    {
        const int row = t >> 3;            // 0..63
        const int e = e0 + row;
        const bool ev = e < n_edges;
        const int ss = sS[row], rr = rS[row];
        char* xrow = lds + REG0 + row * XS_B;
        const int c0 = (t & 7) * 4;
#pragma unroll
        for (int jj = 0; jj < 12; ++jj) {
            const int col = c0 + 32 * jj;   // jj<4: edge; jj<8: sender; else recv
            float4 v = make_float4(0.f, 0.f, 0.f, 0.f);
            if (ev) {
                if (jj < 4)
                    v = *(const float4*)(edge_embeds + (size_t)e * 128 + col);
                else if (jj < 8)
                    v = *(const float4*)(embed_table + (size_t)ss * 256 + (col - 128));
                else
                    v = *(const float4*)(embed_table + (size_t)rr * 256 + 128 + (col - 256));
            }
            BF4 pk;
            pk.a = __float22bfloat162_rn(make_float2(v.x, v.y));
            pk.b = __float22bfloat162_rn(make_float2(v.z, v.w));
            *(BF4*)(xrow + col * 2) = pk;
        }
    }
    __syncthreads();

    const char* wp0 = Wp;
    const char* wp1 = Wp + 196608;
    const char* wp2 = Wp + 262144;

    f32x4 acc[4];

    // ---- GEMM1: X[64,384] @ W0 -> H0 ----
#pragma unroll
    for (int mt = 0; mt < 4; ++mt) acc[mt] = (f32x4){0.f, 0.f, 0.f, 0.f};
    gemm_tiles(lds + REG0, XS_B, wp0, 8, 12, w, lane, acc);
    __syncthreads();                       // Xb dead before H0f overwrite
    dump_acc(lds + REG0, w, lane, acc, b0[w * 16 + lr]);
    __syncthreads();
    ln_silu_bf(lds + REG0, lds + REG1, ln0s, ln0b, t);   // H0f -> H0b
    __syncthreads();

    // ---- GEMM2: H0[64,128] @ W1 -> H1 ----
#pragma unroll
    for (int mt = 0; mt < 4; ++mt) acc[mt] = (f32x4){0.f, 0.f, 0.f, 0.f};
    gemm_tiles(lds + REG1, HS_B, wp1, 8, 4, w, lane, acc);
    // no barrier: dump writes REG0 (H0f), whose readers finished before the
    // previous barrier; GEMM2 read REG1 only.
    dump_acc(lds + REG0, w, lane, acc, b1[w * 16 + lr]);
    __syncthreads();
    ln_silu_bf(lds + REG0, lds + REG1, ln1s, ln1b, t);   // H1f -> H1b
    __syncthreads();

    // ---- GEMM3: H1[64,128] @ W2 -> F (x0.2), direct global stores ----
#pragma unroll
    for (int p = 0; p < 2; ++p) {
        const int nt = w + 8 * p;
        if (nt >= 10) break;
#pragma unroll
        for (int mt = 0; mt < 4; ++mt) acc[mt] = (f32x4){0.f, 0.f, 0.f, 0.f};
        gemm_tiles(lds + REG1, HS_B, wp2, 10, 4, nt, lane, acc);
        const float bb = b2[nt * 16 + lr];
#pragma unroll
        for (int mt = 0; mt < 4; ++mt)
#pragma unroll
            for (int i = 0; i < 4; ++i) {
                const int e = e0 + mt * 16 + lk * 4 + i;
                if (e < n_edges)
                    F[(size_t)e * NOUT + nt * 16 + lr] = (acc[mt][i] + bb) * 0.2f;
            }
    }
}

// ---------------------------------------------------------------- CSR build
__global__ void hist_kernel(const int* __restrict__ recv, int* __restrict__ cnt, int n_edges)
{
    const int e = blockIdx.x * 256 + threadIdx.x;
    if (e < n_edges) atomicAdd(&cnt[recv[e]], 1);
}

#define SCAN_T 1024
#define SCAN_CH 20
__global__ __launch_bounds__(SCAN_T)
void scan_kernel(const int* __restrict__ cnt, int* __restrict__ offsets, int n_nodes)
{
    __shared__ int waveSum[SCAN_T / 64];
    const int t = threadIdx.x;
    const int base = t * SCAN_CH;
    int local[SCAN_CH];
    int s = 0;
#pragma unroll
    for (int j = 0; j < SCAN_CH; ++j) {
        const int v = (base + j < n_nodes) ? cnt[base + j] : 0;
        local[j] = s;
        s += v;
    }
    const int lane = t & 63;
    int incl = s;
#pragma unroll
    for (int d = 1; d < 64; d <<= 1) {
        const int u = __shfl_up(incl, d, 64);
        if (lane >= d) incl += u;
    }
    if (lane == 63) waveSum[t >> 6] = incl;
    __syncthreads();
    if (t < SCAN_T / 64) {
        const int v = waveSum[t];
        int incl2 = v;
#pragma unroll
        for (int d = 1; d < SCAN_T / 64; d <<= 1) {
            const int u = __shfl_up(incl2, d, 64);
            if (lane >= d) incl2 += u;
        }
        waveSum[t] = incl2 - v;
    }
    __syncthreads();
    const int threadExcl = waveSum[t >> 6] + (incl - s);
#pragma unroll
    for (int j = 0; j < SCAN_CH; ++j)
        if (base + j < n_nodes) offsets[base + j] = threadExcl + local[j];
    if (t == SCAN_T - 1) offsets[n_nodes] = threadExcl + s;
}

__global__ void scatter_kernel(const int* __restrict__ recv, int* __restrict__ cursor,
                               int* __restrict__ elist, int n_edges)
{
    const int e = blockIdx.x * 256 + threadIdx.x;
    if (e < n_edges) {
        const int p = atomicAdd(&cursor[recv[e]], 1);
        elist[p] = e;
    }
}

// ---------------------------------------------------------------- aggregation
__global__ __launch_bounds__(256)
void agg_kernel(const float* __restrict__ wigner, const float* __restrict__ F,
                const int* __restrict__ offsets, const int* __restrict__ elist,
                float* __restrict__ out)
{
    const int n = blockIdx.x;
    const int t = threadIdx.x;
    __shared__ float wigS[2][128];

    const int beg = offsets[n];
    const int end = offsets[n + 1];

    const int ch = t & 31;
    const int k0 = t >> 5;
    float a0 = 0.f, a1 = 0.f, a2 = 0.f, a3 = 0.f;

    float f[5];
    if (beg < end) {
        const int e = elist[beg];
        if (t < 125) wigS[0][t] = wigner[(size_t)e * WIG_ROW + (t / 5) * WIG_LD + (t % 5)];
        const float* Fp = F + (size_t)e * NOUT + ch;
#pragma unroll
        for (int m = 0; m < 5; ++m) f[m] = Fp[m * 32];
    }

    int buf = 0;
    for (int i = beg; i < end; ++i) {
        __syncthreads();
        float fc[5];
#pragma unroll
        for (int m = 0; m < 5; ++m) fc[m] = f[m];
        if (i + 1 < end) {
            const int e = elist[i + 1];
            if (t < 125) wigS[buf ^ 1][t] = wigner[(size_t)e * WIG_ROW + (t / 5) * WIG_LD + (t % 5)];
            const float* Fp = F + (size_t)e * NOUT + ch;
#pragma unroll
            for (int m = 0; m < 5; ++m) f[m] = Fp[m * 32];
        }
        const float* wp = &wigS[buf][0];
        { const float* wq = wp + k0 * 5;        a0 += wq[0]*fc[0] + wq[1]*fc[1] + wq[2]*fc[2] + wq[3]*fc[3] + wq[4]*fc[4]; }
        { const float* wq = wp + (k0 + 8) * 5;  a1 += wq[0]*fc[0] + wq[1]*fc[1] + wq[2]*fc[2] + wq[3]*fc[3] + wq[4]*fc[4]; }
        { const float* wq = wp + (k0 + 16) * 5; a2 += wq[0]*fc[0] + wq[1]*fc[1] + wq[2]*fc[2] + wq[3]*fc[3] + wq[4]*fc[4]; }
        if (t < 32) { const float* wq = wp + 120; a3 += wq[0]*fc[0] + wq[1]*fc[1] + wq[2]*fc[2] + wq[3]*fc[3] + wq[4]*fc[4]; }
        buf ^= 1;
    }

    float* orow = out + (size_t)n * (NKF * 32);
    orow[t] = a0;
    orow[t + 256] = a1;
    orow[t + 512] = a2;
    if (t < 32) orow[t + 768] = a3;
}

// ---------------------------------------------------------------- fallback (round-0)
#define EB 32
__device__ __forceinline__ void ln_silu_f(float (*Bx)[HDIM], const float* __restrict__ s,
                                          const float* __restrict__ b, int t)
{
    const int r = t >> 3;
    const int j = t & 7;
    float v[16];
    float sum = 0.f, sq = 0.f;
#pragma unroll
    for (int q = 0; q < 16; ++q) { v[q] = Bx[r][j*16+q]; sum += v[q]; sq = fmaf(v[q], v[q], sq); }
#pragma unroll
    for (int m = 1; m < 8; m <<= 1) { sum += __shfl_xor(sum, m, 64); sq += __shfl_xor(sq, m, 64); }
    const float mu = sum * (1.f/HDIM);
    const float var = sq * (1.f/HDIM) - mu*mu;
    const float rstd = rsqrtf(var + 1e-6f);
#pragma unroll
    for (int q = 0; q < 16; ++q) {
        const int cc = j*16+q;
        const float y = (v[q]-mu)*rstd*s[cc]+b[cc];
        Bx[r][cc] = y / (1.f + __expf(-y));
    }
}

__global__ __launch_bounds__(256, 2)
void edge_fused_kernel(
    const int* __restrict__ species, const float* __restrict__ edge_embeds,
    const int* __restrict__ senders, const int* __restrict__ receivers,
    const float* __restrict__ wigner, const float* __restrict__ embed_table,
    const float* __restrict__ W0, const float* __restrict__ b0,
    const float* __restrict__ ln0s, const float* __restrict__ ln0b,
    const float* __restrict__ W1, const float* __restrict__ b1,
    const float* __restrict__ ln1s, const float* __restrict__ ln1b,
    const float* __restrict__ W2, const float* __restrict__ b2,
    float* __restrict__ out, int n_edges)
{
    __shared__ float A[EB][DIN];
    __shared__ float Bx[EB][HDIM];
    __shared__ int sSpec[EB], rSpec[EB], rNode[EB];
    const int t = threadIdx.x;
    const int e0 = blockIdx.x * EB;
    if (t < EB) {
        const int e = e0 + t;
        int s = 0, r = 0;
        if (e < n_edges) { s = senders[e]; r = receivers[e]; }
        sSpec[t] = species[s]; rSpec[t] = species[r]; rNode[t] = r;
    }
    __syncthreads();
    for (int idx = t; idx < EB * DIN; idx += 256) {
        const int r = idx / DIN;
        const int i = idx - r * DIN;
        const int e = e0 + r;
        float v = 0.f;
        if (e < n_edges) {
            if (i < HDIM) v = edge_embeds[(size_t)e * HDIM + i];
            else if (i < 2*HDIM) v = embed_table[(size_t)sSpec[r]*256 + (i-HDIM)];
            else v = embed_table[(size_t)rSpec[r]*256 + HDIM + (i-2*HDIM)];
        }
        A[r][i] = v;
    }
    __syncthreads();
    const int c = t & (HDIM-1);
    const int g = t >> 7;
    float acc[16];
#pragma unroll
    for (int q = 0; q < 16; ++q) acc[q] = 0.f;
    for (int it = 0; it < DIN/4; ++it) {
        const float wa = W0[(4*it+0)*HDIM+c], wb = W0[(4*it+1)*HDIM+c];
        const float wc = W0[(4*it+2)*HDIM+c], wd = W0[(4*it+3)*HDIM+c];
#pragma unroll
        for (int q = 0; q < 16; ++q) {
            const float4 x4 = *reinterpret_cast<const float4*>(&A[g*16+q][4*it]);
            acc[q] = fmaf(x4.x, wa, fmaf(x4.y, wb, fmaf(x4.z, wc, fmaf(x4.w, wd, acc[q]))));
        }
    }
    { const float bb = b0[c];
#pragma unroll
      for (int q = 0; q < 16; ++q) Bx[g*16+q][c] = acc[q] + bb; }
    __syncthreads(); ln_silu_f(Bx, ln0s, ln0b, t); __syncthreads();
#pragma unroll
    for (int q = 0; q < 16; ++q) acc[q] = 0.f;
    for (int it = 0; it < HDIM/4; ++it) {
        const float wa = W1[(4*it+0)*HDIM+c], wb = W1[(4*it+1)*HDIM+c];
        const float wc = W1[(4*it+2)*HDIM+c], wd = W1[(4*it+3)*HDIM+c];
#pragma unroll
        for (int q = 0; q < 16; ++q) {
            const float4 x4 = *reinterpret_cast<const float4*>(&Bx[g*16+q][4*it]);
            acc[q] = fmaf(x4.x, wa, fmaf(x4.y, wb, fmaf(x4.z, wc, fmaf(x4.w, wd, acc[q]))));
        }
    }
    __syncthreads();
    { const float bb = b1[c];
#pragma unroll
      for (int q = 0; q < 16; ++q) Bx[g*16+q][c] = acc[q] + bb; }
    __syncthreads(); ln_silu_f(Bx, ln1s, ln1b, t); __syncthreads();
    float* Ff = &A[0][0];
    {
        float a2[16];
#pragma unroll
        for (int q = 0; q < 16; ++q) a2[q] = 0.f;
        for (int it = 0; it < HDIM/4; ++it) {
            const float wa = W2[(4*it+0)*NOUT+c], wb = W2[(4*it+1)*NOUT+c];
            const float wc = W2[(4*it+2)*NOUT+c], wd = W2[(4*it+3)*NOUT+c];
#pragma unroll
            for (int q = 0; q < 16; ++q) {
                const float4 x4 = *reinterpret_cast<const float4*>(&Bx[g*16+q][4*it]);
                a2[q] = fmaf(x4.x, wa, fmaf(x4.y, wb, fmaf(x4.z, wc, fmaf(x4.w, wd, a2[q]))));
            }
        }
        const float bb = b2[c];
#pragma unroll
        for (int q = 0; q < 16; ++q) Ff[(g*16+q)*NOUT+c] = (a2[q]+bb)*0.2f;
    }
    {
        const int c2 = HDIM + (t & 31);
        const int g8 = t >> 5;
        float a2[4] = {0.f, 0.f, 0.f, 0.f};
        for (int it = 0; it < HDIM/4; ++it) {
            const float wa = W2[(4*it+0)*NOUT+c2], wb = W2[(4*it+1)*NOUT+c2];
            const float wc = W2[(4*it+2)*NOUT+c2], wd = W2[(4*it+3)*NOUT+c2];
#pragma unroll
            for (int q = 0; q < 4; ++q) {
                const float4 x4 = *reinterpret_cast<const float4*>(&Bx[g8*4+q][4*it]);
                a2[q] = fmaf(x4.x, wa, fmaf(x4.y, wb, fmaf(x4.z, wc, fmaf(x4.w, wd, a2[q]))));
            }
        }
        const float bb = b2[c2];
#pragma unroll
        for (int q = 0; q < 4; ++q) Ff[(g8*4+q)*NOUT+c2] = (a2[q]+bb)*0.2f;
    }
    __syncthreads();
    for (int r = 0; r < EB; ++r) {
        const int e = e0 + r;
        if (e >= n_edges) break;
        const float* wrow = wigner + (size_t)e * WIG_ROW;
        float* orow = out + (size_t)rNode[r] * (NKF*32);
        const float* Fr = Ff + r * NOUT;
#pragma unroll
        for (int jj = 0; jj < 4; ++jj) {
            const int p = t + 256*jj;
            if (p < NKF*32) {
                const int k = p >> 5, chh = p & 31;
                float val = 0.f;
#pragma unroll
                for (int m = 0; m < 5; ++m)
                    val = fmaf(wrow[k*WIG_LD+m], Fr[m*32+chh], val);
                atomicAdd(&orow[p], val);
            }
        }
    }
}

// ---------------------------------------------------------------- launch
extern "C" void kernel_launch(void* const* d_in, const int* in_sizes, int n_in,
                              void* d_out, int out_size, void* d_ws, size_t ws_size,
                              hipStream_t stream)
{
    const int*   species     = (const int*)d_in[0];
    const float* edge_embeds = (const float*)d_in[1];
    const int*   senders     = (const int*)d_in[2];
    const int*   receivers   = (const int*)d_in[3];
    const float* wigner      = (const float*)d_in[4];
    const float* embed_table = (const float*)d_in[5];
    const float* W0 = (const float*)d_in[6];
    const float* b0 = (const float*)d_in[7];
    const float* ln0s = (const float*)d_in[8];
    const float* ln0b = (const float*)d_in[9];
    const float* W1 = (const float*)d_in[10];
    const float* b1 = (const float*)d_in[11];
    const float* ln1s = (const float*)d_in[12];
    const float* ln1b = (const float*)d_in[13];
    const float* W2 = (const float*)d_in[14];
    const float* b2 = (const float*)d_in[15];
    float* out = (float*)d_out;

    const int n_nodes = in_sizes[0];
    const int n_edges = in_sizes[2];

    const size_t wpBytes   = 344064;
    const size_t fBytes    = (size_t)n_edges * NOUT * sizeof(float);
    const size_t offBytes  = (size_t)(n_nodes + 1) * sizeof(int);
    const size_t curBytes  = (size_t)n_nodes * sizeof(int);
    const size_t listBytes = (size_t)n_edges * sizeof(int);
    const size_t need = wpBytes + fBytes + offBytes + curBytes + listBytes + 64;

    if (ws_size < need || n_nodes > SCAN_T * SCAN_CH) {
        hipMemsetAsync(out, 0, (size_t)out_size * sizeof(float), stream);
        const int nblocks = (n_edges + EB - 1) / EB;
        hipLaunchKernelGGL(edge_fused_kernel, dim3(nblocks), dim3(256), 0, stream,
                           species, edge_embeds, senders, receivers, wigner, embed_table,
                           W0, b0, ln0s, ln0b, W1, b1, ln1s, ln1b, W2, b2, out, n_edges);
        return;
    }

    char* ws = (char*)d_ws;
    unsigned short* Wp = (unsigned short*)ws;
    float* F       = (float*)(ws + wpBytes);
    int*   offsets = (int*)(ws + wpBytes + fBytes);
    int*   cursor  = (int*)(ws + wpBytes + fBytes + offBytes);
    int*   elist   = (int*)(ws + wpBytes + fBytes + offBytes + curBytes);

    const int egrid = (n_edges + 255) / 256;

    // weight repack (tiny; L2-resident afterwards)
    hipLaunchKernelGGL(repack_w, dim3(336), dim3(256), 0, stream, W0, W1, W2, Wp);

    // CSR build
    hipMemsetAsync(cursor, 0, curBytes, stream);
    hipLaunchKernelGGL(hist_kernel, dim3(egrid), dim3(256), 0, stream,
                       receivers, cursor, n_edges);
    hipLaunchKernelGGL(scan_kernel, dim3(1), dim3(SCAN_T), 0, stream,
                       cursor, offsets, n_nodes);
    hipMemcpyAsync(cursor, offsets, curBytes, hipMemcpyDeviceToDevice, stream);
    hipLaunchKernelGGL(scatter_kernel, dim3(egrid), dim3(256), 0, stream,
                       receivers, cursor, elist, n_edges);

    // MLP (MFMA) -> F
    const int mblocks = (n_edges + MB - 1) / MB;
    hipLaunchKernelGGL(mlp_mfma, dim3(mblocks), dim3(MTHREADS), 0, stream,
                       species, edge_embeds, senders, receivers, embed_table,
                       (const char*)Wp, b0, ln0s, ln0b, b1, ln1s, ln1b, b2, F, n_edges);

    // gather-aggregate -> out
    hipLaunchKernelGGL(agg_kernel, dim3(n_nodes), dim3(256), 0, stream,
                       wigner, F, offsets, elist, out);
}

// Round 7
// 524.117 us; speedup vs baseline: 5.4572x; 1.0064x over previous
//
#include <hip/hip_runtime.h>
#include <hip/hip_bf16.h>
#include <cstddef>

// EdgeDegreeEmbedding, round 6.
// Round-4/5's barrier-free MLP failed absmax (~0.23) for reasons not yet
// localized; reverting to round-3's PROVEN numerics/structure (passed, 0.031)
// with two mechanical changes:
//   - mlp: MB=32, 256 thr, LDS 34KB -> 4 blocks/CU (was 2). Wave sweeps
//     nt = {w, w+4} (G1/G2) and {w, w+4, w+8} (G3). Same staging, LN, packing.
//   - agg: 128 thr/node (was 256): wigner load 125/128 lanes, 2-wave barriers,
//     thread (k0=t>>5, ch=t&31) accumulates k = k0+4j.
// CSR: hist + scan(writes offsets+cursor) + scatter. Fallback: round-0 kernel.

#define MB 32
#define MTHREADS 256
#define DIN 384
#define HDIM 128
#define NOUT 160
#define NKF 25
#define WIG_LD 19
#define WIG_ROW 475

#define WP1OFF 196608    // W0 pack: 12kt*8nt*2*1024 B
#define WP2OFF 262144    // + W1 pack: 4*8*2*1024 = 65536
#define WPBYTES 344064   // + W2 pack: 4*10*2*1024 = 81920

// LDS layout (bytes)
#define XS_B   784       // Xb row stride: (384+8) bf16
#define FS_B   528       // Hf row stride: 132 f32
#define HS_B   272       // Hb row stride: (128+8) bf16
#define REG0   0         // Xb (32*784=25088) / Hf (32*528=16896)
#define REG1   25088     // Hb (32*272=8704)
#define METAS  33792     // sS[32]
#define METAR  33920     // rS[32]
#define LDSSZ  34048

typedef __attribute__((ext_vector_type(8))) short short8;
typedef __attribute__((ext_vector_type(4))) float f32x4;

struct BF4 { __hip_bfloat162 a, b; };   // 8 B = 4 bf16

__device__ __forceinline__ unsigned short f2bf(float f)
{
    union { float f; unsigned u; } x; x.f = f;
    unsigned r = x.u + 0x7fffu + ((x.u >> 16) & 1u);
    return (unsigned short)(r >> 16);
}

// ---------------------------------------------------------------- W repack
// (round-3 verbatim) B-frag block (1024 B) = one (kt, nt, term): 64 lanes x
// 8 bf16; lane l holds B[kt*32 + 8*(l>>4)+i][nt*16 + (l&15)]. All hi+lo.
__global__ void repack_w(const float* __restrict__ W0, const float* __restrict__ W1,
                         const float* __restrict__ W2, unsigned short* __restrict__ Wp)
{
    const int id = blockIdx.x * 256 + threadIdx.x;
    const float* W; int k, n, NT, N; size_t base;  // base in ushort units
    if (id < 49152)      { W = W0; k = id >> 7;  n = id & 127;  NT = 8;  N = 128; base = 0; }
    else if (id < 65536) { int r = id - 49152; W = W1; k = r >> 7; n = r & 127; NT = 8; N = 128; base = 98304; }
    else if (id < 86016) { int r = id - 65536; W = W2; k = r / 160; n = r - 160 * k; NT = 10; N = 160; base = 131072; }
    else return;
    const float w = W[(size_t)k * N + n];
    const unsigned short hi = f2bf(w);
    union { unsigned u; float f; } hf; hf.u = ((unsigned)hi) << 16;
    const unsigned short lo = f2bf(w - hf.f);
    const int kt = k >> 5, kk = k & 31;
    const int l = ((kk >> 3) << 4) | (n & 15);
    const int i = kk & 7;
    const int nt = n >> 4;
    const size_t o = base + (size_t)((kt * NT + nt) * 2) * 512 + l * 8 + i;
    Wp[o] = hi;
    Wp[o + 512] = lo;
}

// ---------------------------------------------------------------- GEMM core
// 2 M-tiles (32 rows), N-tile nt, hi+lo terms. (round-3 gemm_tiles, mt 4->2)
__device__ __forceinline__ void gemm_tiles2(const char* __restrict__ ldsA, int astride,
                                            const char* __restrict__ wp, int NT, int KT,
                                            int nt, int lane, f32x4 acc[2])
{
    const int lr = lane & 15, lk = lane >> 4;
    for (int kt = 0; kt < KT; ++kt) {
        const char* wb = wp + (size_t)((kt * NT + nt) * 2) * 1024 + lane * 16;
        const short8 bh = *(const short8*)(wb);
        const short8 bl = *(const short8*)(wb + 1024);
        short8 a[2];
#pragma unroll
        for (int mt = 0; mt < 2; ++mt)
            a[mt] = *(const short8*)(ldsA + (mt * 16 + lr) * astride + kt * 64 + lk * 16);
#pragma unroll
        for (int mt = 0; mt < 2; ++mt) {
            acc[mt] = __builtin_amdgcn_mfma_f32_16x16x32_bf16(a[mt], bh, acc[mt], 0, 0, 0);
            acc[mt] = __builtin_amdgcn_mfma_f32_16x16x32_bf16(a[mt], bl, acc[mt], 0, 0, 0);
        }
    }
}

// Combined 2-nt variant (shares A-frag LDS reads): nt = ntbase, ntbase+4.
__device__ __forceinline__ void gemm_tiles2x2(const char* __restrict__ ldsA, int astride,
                                              const char* __restrict__ wp, int NT, int KT,
                                              int ntbase, int lane, f32x4 acc[2][2])
{
    const int lr = lane & 15, lk = lane >> 4;
    for (int kt = 0; kt < KT; ++kt) {
        short8 a[2];
#pragma unroll
        for (int mt = 0; mt < 2; ++mt)
            a[mt] = *(const short8*)(ldsA + (mt * 16 + lr) * astride + kt * 64 + lk * 16);
#pragma unroll
        for (int p = 0; p < 2; ++p) {
            const int nt = ntbase + 4 * p;
            const char* wb = wp + (size_t)((kt * NT + nt) * 2) * 1024 + lane * 16;
            const short8 bh = *(const short8*)(wb);
            const short8 bl = *(const short8*)(wb + 1024);
#pragma unroll
            for (int mt = 0; mt < 2; ++mt) {
                acc[p][mt] = __builtin_amdgcn_mfma_f32_16x16x32_bf16(a[mt], bh, acc[p][mt], 0, 0, 0);
                acc[p][mt] = __builtin_amdgcn_mfma_f32_16x16x32_bf16(a[mt], bl, acc[p][mt], 0, 0, 0);
            }
        }
    }
}

__device__ __forceinline__ void dump_acc2(char* Hf, int nt, int lane, const f32x4 acc[2],
                                          const float bias)
{
    const int lr = lane & 15, lk = lane >> 4;
#pragma unroll
    for (int mt = 0; mt < 2; ++mt)
#pragma unroll
        for (int i = 0; i < 4; ++i)
            *(float*)(Hf + (mt * 16 + lk * 4 + i) * FS_B + (nt * 16 + lr) * 4) = acc[mt][i] + bias;
}

// LN + silu (round-3 verbatim): read f32 (FS_B), write packed bf16 (HS_B).
// 256 threads, 32 rows, 8 threads/row x 16 channels.
__device__ __forceinline__ void ln_silu_bf(const char* Hf, char* Hb,
                                           const float* __restrict__ s,
                                           const float* __restrict__ b, int t)
{
    const int j = t & 7;
    const int r = t >> 3;
    float v[16];
    float sum = 0.f, sq = 0.f;
#pragma unroll
    for (int q4 = 0; q4 < 4; ++q4) {
        const float4 x4 = *(const float4*)(Hf + r * FS_B + (j * 16 + q4 * 4) * 4);
        v[q4 * 4 + 0] = x4.x; v[q4 * 4 + 1] = x4.y;
        v[q4 * 4 + 2] = x4.z; v[q4 * 4 + 3] = x4.w;
    }
#pragma unroll
    for (int q = 0; q < 16; ++q) { sum += v[q]; sq = fmaf(v[q], v[q], sq); }
#pragma unroll
    for (int m = 1; m < 8; m <<= 1) {
        sum += __shfl_xor(sum, m, 64);
        sq  += __shfl_xor(sq,  m, 64);
    }
    const float mu = sum * (1.f / 128.f);
    const float var = sq * (1.f / 128.f) - mu * mu;
    const float rstd = rsqrtf(var + 1e-6f);
#pragma unroll
    for (int q = 0; q < 16; q += 2) {
        const int c0 = j * 16 + q;
        float y0 = (v[q] - mu) * rstd * s[c0] + b[c0];
        float y1 = (v[q + 1] - mu) * rstd * s[c0 + 1] + b[c0 + 1];
        y0 = y0 / (1.f + __expf(-y0));
        y1 = y1 / (1.f + __expf(-y1));
        *(__hip_bfloat162*)(Hb + r * HS_B + c0 * 2) =
            __float22bfloat162_rn(make_float2(y0, y1));
    }
}

// ---------------------------------------------------------------- MLP (MFMA)
__global__ __launch_bounds__(MTHREADS, 4)
void mlp_mfma(
    const int* __restrict__ species,
    const float* __restrict__ edge_embeds,
    const int* __restrict__ senders,
    const int* __restrict__ receivers,
    const float* __restrict__ embed_table,
    const char* __restrict__ Wp,
    const float* __restrict__ b0, const float* __restrict__ ln0s, const float* __restrict__ ln0b,
    const float* __restrict__ b1, const float* __restrict__ ln1s, const float* __restrict__ ln1b,
    const float* __restrict__ b2,
    float* __restrict__ F,
    int n_edges)
{
    __shared__ alignas(16) char lds[LDSSZ];
    int* sS = (int*)(lds + METAS);
    int* rS = (int*)(lds + METAR);

    const int t = threadIdx.x;
    const int e0 = blockIdx.x * MB;
    const int w = t >> 6;
    const int lane = t & 63;
    const int lr = lane & 15, lk = lane >> 4;

    if (t < MB) {
        const int e = e0 + t;
        int s = 0, r = 0;
        if (e < n_edges) { s = senders[e]; r = receivers[e]; }
        sS[t] = species[s];
        rS[t] = species[r];
    }
    __syncthreads();

    // ---- stage X -> bf16 LDS (8 threads/row, 4-col chunks, stride 32) ----
    {
        const int row = t >> 3;            // 0..31
        const int e = e0 + row;
        const bool ev = e < n_edges;
        const int ss = sS[row], rr = rS[row];
        char* xrow = lds + REG0 + row * XS_B;
        const int c0 = (t & 7) * 4;
#pragma unroll
        for (int jj = 0; jj < 12; ++jj) {
            const int col = c0 + 32 * jj;   // jj<4: edge; jj<8: sender; else recv
            float4 v = make_float4(0.f, 0.f, 0.f, 0.f);
            if (ev) {
                if (jj < 4)
                    v = *(const float4*)(edge_embeds + (size_t)e * 128 + col);
                else if (jj < 8)
                    v = *(const float4*)(embed_table + (size_t)ss * 256 + (col - 128));
                else
                    v = *(const float4*)(embed_table + (size_t)rr * 256 + 128 + (col - 256));
            }
            BF4 pk;
            pk.a = __float22bfloat162_rn(make_float2(v.x, v.y));
            pk.b = __float22bfloat162_rn(make_float2(v.z, v.w));
            *(BF4*)(xrow + col * 2) = pk;
        }
    }
    __syncthreads();

    const char* wp0 = Wp;
    const char* wp1 = Wp + WP1OFF;
    const char* wp2 = Wp + WP2OFF;

    f32x4 acc[2][2];

    // ---- GEMM1: X[32,384] @ W0 -> H0 (wave sweeps nt = w, w+4) ----
#pragma unroll
    for (int p = 0; p < 2; ++p)
#pragma unroll
        for (int mt = 0; mt < 2; ++mt) acc[p][mt] = (f32x4){0.f, 0.f, 0.f, 0.f};
    gemm_tiles2x2(lds + REG0, XS_B, wp0, 8, 12, w, lane, acc);
    __syncthreads();                       // Xb dead before Hf overwrite
#pragma unroll
    for (int p = 0; p < 2; ++p) {
        const int nt = w + 4 * p;
        dump_acc2(lds + REG0, nt, lane, acc[p], b0[nt * 16 + lr]);
    }
    __syncthreads();
    ln_silu_bf(lds + REG0, lds + REG1, ln0s, ln0b, t);   // Hf -> Hb
    __syncthreads();

    // ---- GEMM2: H0[32,128] @ W1 -> H1 ----
#pragma unroll
    for (int p = 0; p < 2; ++p)
#pragma unroll
        for (int mt = 0; mt < 2; ++mt) acc[p][mt] = (f32x4){0.f, 0.f, 0.f, 0.f};
    gemm_tiles2x2(lds + REG1, HS_B, wp1, 8, 4, w, lane, acc);
    // no barrier: dump writes REG0 (Hf), whose readers (ln) finished before
    // the previous barrier; GEMM2 read REG1 only.  (round-3 ordering)
#pragma unroll
    for (int p = 0; p < 2; ++p) {
        const int nt = w + 4 * p;
        dump_acc2(lds + REG0, nt, lane, acc[p], b1[nt * 16 + lr]);
    }
    __syncthreads();
    ln_silu_bf(lds + REG0, lds + REG1, ln1s, ln1b, t);   // Hf -> Hb
    __syncthreads();

    // ---- GEMM3: H1[32,128] @ W2 -> F (x0.2), nt = w, w+4, w+8 (<10) ----
#pragma unroll
    for (int p = 0; p < 3; ++p) {
        const int nt = w + 4 * p;
        if (nt >= 10) break;
        f32x4 a3[2];
#pragma unroll
        for (int mt = 0; mt < 2; ++mt) a3[mt] = (f32x4){0.f, 0.f, 0.f, 0.f};
        gemm_tiles2(lds + REG1, HS_B, wp2, 10, 4, nt, lane, a3);
        const float bb = b2[nt * 16 + lr];
#pragma unroll
        for (int mt = 0; mt < 2; ++mt)
#pragma unroll
            for (int i = 0; i < 4; ++i) {
                const int e = e0 + mt * 16 + lk * 4 + i;
                if (e < n_edges)
                    F[(size_t)e * NOUT + nt * 16 + lr] = (a3[mt][i] + bb) * 0.2f;
            }
    }
}

// ---------------------------------------------------------------- CSR build
__global__ void hist_kernel(const int* __restrict__ recv, int* __restrict__ cnt, int n_edges)
{
    const int e = blockIdx.x * 256 + threadIdx.x;
    if (e < n_edges) atomicAdd(&cnt[recv[e]], 1);
}

#define SCAN_T 1024
#define SCAN_CH 20
__global__ __launch_bounds__(SCAN_T)
void scan_kernel(const int* __restrict__ cnt, int* __restrict__ offsets,
                 int* __restrict__ cursor, int n_nodes)
{
    __shared__ int waveSum[SCAN_T / 64];
    const int t = threadIdx.x;
    const int base = t * SCAN_CH;
    int local[SCAN_CH];
    int s = 0;
#pragma unroll
    for (int j = 0; j < SCAN_CH; ++j) {
        const int v = (base + j < n_nodes) ? cnt[base + j] : 0;
        local[j] = s;
        s += v;
    }
    const int lane = t & 63;
    int incl = s;
#pragma unroll
    for (int d = 1; d < 64; d <<= 1) {
        const int u = __shfl_up(incl, d, 64);
        if (lane >= d) incl += u;
    }
    if (lane == 63) waveSum[t >> 6] = incl;
    __syncthreads();
    if (t < SCAN_T / 64) {
        const int v = waveSum[t];
        int incl2 = v;
#pragma unroll
        for (int d = 1; d < SCAN_T / 64; d <<= 1) {
            const int u = __shfl_up(incl2, d, 64);
            if (lane >= d) incl2 += u;
        }
        waveSum[t] = incl2 - v;
    }
    __syncthreads();
    const int threadExcl = waveSum[t >> 6] + (incl - s);
#pragma unroll
    for (int j = 0; j < SCAN_CH; ++j)
        if (base + j < n_nodes) {
            const int o = threadExcl + local[j];
            offsets[base + j] = o;
            cursor[base + j] = o;
        }
    if (t == SCAN_T - 1) offsets[n_nodes] = threadExcl + s;
}

__global__ void scatter_kernel(const int* __restrict__ recv, int* __restrict__ cursor,
                               int* __restrict__ elist, int n_edges)
{
    const int e = blockIdx.x * 256 + threadIdx.x;
    if (e < n_edges) {
        const int p = atomicAdd(&cursor[recv[e]], 1);
        elist[p] = e;
    }
}

// ---------------------------------------------------------------- aggregation
// 128 threads per node: ch = t&31, k0 = t>>5; thread accumulates k = k0+4j.
__global__ __launch_bounds__(128)
void agg_kernel(const float* __restrict__ wigner, const float* __restrict__ F,
                const int* __restrict__ offsets, const int* __restrict__ elist,
                float* __restrict__ out)
{
    const int n = blockIdx.x;
    const int t = threadIdx.x;
    __shared__ float wigS[2][128];   // 125 used: [k*5+m]

    const int beg = offsets[n];
    const int end = offsets[n + 1];

    const int ch = t & 31;
    const int k0 = t >> 5;           // 0..3
    float a[7];
#pragma unroll
    for (int j = 0; j < 7; ++j) a[j] = 0.f;

    float f[5];
    if (beg < end) {
        const int e = elist[beg];
        if (t < 125) wigS[0][t] = wigner[(size_t)e * WIG_ROW + (t / 5) * WIG_LD + (t % 5)];
        const float* Fp = F + (size_t)e * NOUT + ch;
#pragma unroll
        for (int m = 0; m < 5; ++m) f[m] = Fp[m * 32];
    }

    int buf = 0;
    for (int i = beg; i < end; ++i) {
        __syncthreads();
        float fc[5];
#pragma unroll
        for (int m = 0; m < 5; ++m) fc[m] = f[m];
        if (i + 1 < end) {
            const int e = elist[i + 1];
            if (t < 125) wigS[buf ^ 1][t] = wigner[(size_t)e * WIG_ROW + (t / 5) * WIG_LD + (t % 5)];
            const float* Fp = F + (size_t)e * NOUT + ch;
#pragma unroll
            for (int m = 0; m < 5; ++m) f[m] = Fp[m * 32];
        }
        const float* wp = &wigS[buf][0];
#pragma unroll
        for (int j = 0; j < 7; ++j) {
            const int k = k0 + 4 * j;
            if (k < NKF) {
                const float* wq = wp + k * 5;
                a[j] += wq[0] * fc[0] + wq[1] * fc[1] + wq[2] * fc[2]
                      + wq[3] * fc[3] + wq[4] * fc[4];
            }
        }
        buf ^= 1;
    }

    float* orow = out + (size_t)n * (NKF * 32);
#pragma unroll
    for (int j = 0; j < 7; ++j) {
        const int k = k0 + 4 * j;
        if (k < NKF) orow[k * 32 + ch] = a[j];
    }
}

// ---------------------------------------------------------------- fallback (round-0)
#define EB 32
__device__ __forceinline__ void ln_silu_f(float (*Bx)[HDIM], const float* __restrict__ s,
                                          const float* __restrict__ b, int t)
{
    const int r = t >> 3;
    const int j = t & 7;
    float v[16];
    float sum = 0.f, sq = 0.f;
#pragma unroll
    for (int q = 0; q < 16; ++q) { v[q] = Bx[r][j*16+q]; sum += v[q]; sq = fmaf(v[q], v[q], sq); }
#pragma unroll
    for (int m = 1; m < 8; m <<= 1) { sum += __shfl_xor(sum, m, 64); sq += __shfl_xor(sq, m, 64); }
    const float mu = sum * (1.f/HDIM);
    const float var = sq * (1.f/HDIM) - mu*mu;
    const float rstd = rsqrtf(var + 1e-6f);
#pragma unroll
    for (int q = 0; q < 16; ++q) {
        const int cc = j*16+q;
        const float y = (v[q]-mu)*rstd*s[cc]+b[cc];
        Bx[r][cc] = y / (1.f + __expf(-y));
    }
}

__global__ __launch_bounds__(256, 2)
void edge_fused_kernel(
    const int* __restrict__ species, const float* __restrict__ edge_embeds,
    const int* __restrict__ senders, const int* __restrict__ receivers,
    const float* __restrict__ wigner, const float* __restrict__ embed_table,
    const float* __restrict__ W0, const float* __restrict__ b0,
    const float* __restrict__ ln0s, const float* __restrict__ ln0b,
    const float* __restrict__ W1, const float* __restrict__ b1,
    const float* __restrict__ ln1s, const float* __restrict__ ln1b,
    const float* __restrict__ W2, const float* __restrict__ b2,
    float* __restrict__ out, int n_edges)
{
    __shared__ float A[EB][DIN];
    __shared__ float Bx[EB][HDIM];
    __shared__ int sSpec[EB], rSpec[EB], rNode[EB];
    const int t = threadIdx.x;
    const int e0 = blockIdx.x * EB;
    if (t < EB) {
        const int e = e0 + t;
        int s = 0, r = 0;
        if (e < n_edges) { s = senders[e]; r = receivers[e]; }
        sSpec[t] = species[s]; rSpec[t] = species[r]; rNode[t] = r;
    }
    __syncthreads();
    for (int idx = t; idx < EB * DIN; idx += 256) {
        const int r = idx / DIN;
        const int i = idx - r * DIN;
        const int e = e0 + r;
        float v = 0.f;
        if (e < n_edges) {
            if (i < HDIM) v = edge_embeds[(size_t)e * HDIM + i];
            else if (i < 2*HDIM) v = embed_table[(size_t)sSpec[r]*256 + (i-HDIM)];
            else v = embed_table[(size_t)rSpec[r]*256 + HDIM + (i-2*HDIM)];
        }
        A[r][i] = v;
    }
    __syncthreads();
    const int c = t & (HDIM-1);
    const int g = t >> 7;
    float acc[16];
#pragma unroll
    for (int q = 0; q < 16; ++q) acc[q] = 0.f;
    for (int it = 0; it < DIN/4; ++it) {
        const float wa = W0[(4*it+0)*HDIM+c], wb = W0[(4*it+1)*HDIM+c];
        const float wc = W0[(4*it+2)*HDIM+c], wd = W0[(4*it+3)*HDIM+c];
#pragma unroll
        for (int q = 0; q < 16; ++q) {
            const float4 x4 = *reinterpret_cast<const float4*>(&A[g*16+q][4*it]);
            acc[q] = fmaf(x4.x, wa, fmaf(x4.y, wb, fmaf(x4.z, wc, fmaf(x4.w, wd, acc[q]))));
        }
    }
    { const float bb = b0[c];
#pragma unroll
      for (int q = 0; q < 16; ++q) Bx[g*16+q][c] = acc[q] + bb; }
    __syncthreads(); ln_silu_f(Bx, ln0s, ln0b, t); __syncthreads();
#pragma unroll
    for (int q = 0; q < 16; ++q) acc[q] = 0.f;
    for (int it = 0; it < HDIM/4; ++it) {
        const float wa = W1[(4*it+0)*HDIM+c], wb = W1[(4*it+1)*HDIM+c];
        const float wc = W1[(4*it+2)*HDIM+c], wd = W1[(4*it+3)*HDIM+c];
#pragma unroll
        for (int q = 0; q < 16; ++q) {
            const float4 x4 = *reinterpret_cast<const float4*>(&Bx[g*16+q][4*it]);
            acc[q] = fmaf(x4.x, wa, fmaf(x4.y, wb, fmaf(x4.z, wc, fmaf(x4.w, wd, acc[q]))));
        }
    }
    __syncthreads();
    { const float bb = b1[c];
#pragma unroll
      for (int q = 0; q < 16; ++q) Bx[g*16+q][c] = acc[q] + bb; }
    __syncthreads(); ln_silu_f(Bx, ln1s, ln1b, t); __syncthreads();
    float* Ff = &A[0][0];
    {
        float a2[16];
#pragma unroll
        for (int q = 0; q < 16; ++q) a2[q] = 0.f;
        for (int it = 0; it < HDIM/4; ++it) {
            const float wa = W2[(4*it+0)*NOUT+c], wb = W2[(4*it+1)*NOUT+c];
            const float wc = W2[(4*it+2)*NOUT+c], wd = W2[(4*it+3)*NOUT+c];
#pragma unroll
            for (int q = 0; q < 16; ++q) {
                const float4 x4 = *reinterpret_cast<const float4*>(&Bx[g*16+q][4*it]);
                a2[q] = fmaf(x4.x, wa, fmaf(x4.y, wb, fmaf(x4.z, wc, fmaf(x4.w, wd, a2[q]))));
            }
        }
        const float bb = b2[c];
#pragma unroll
        for (int q = 0; q < 16; ++q) Ff[(g*16+q)*NOUT+c] = (a2[q]+bb)*0.2f;
    }
    {
        const int c2 = HDIM + (t & 31);
        const int g8 = t >> 5;
        float a2[4] = {0.f, 0.f, 0.f, 0.f};
        for (int it = 0; it < HDIM/4; ++it) {
            const float wa = W2[(4*it+0)*NOUT+c2], wb = W2[(4*it+1)*NOUT+c2];
            const float wc = W2[(4*it+2)*NOUT+c2], wd = W2[(4*it+3)*NOUT+c2];
#pragma unroll
            for (int q = 0; q < 4; ++q) {
                const float4 x4 = *reinterpret_cast<const float4*>(&Bx[g8*4+q][4*it]);
                a2[q] = fmaf(x4.x, wa, fmaf(x4.y, wb, fmaf(x4.z, wc, fmaf(x4.w, wd, a2[q]))));
            }
        }
        const float bb = b2[c2];
#pragma unroll
        for (int q = 0; q < 4; ++q) Ff[(g8*4+q)*NOUT+c2] = (a2[q]+bb)*0.2f;
    }
    __syncthreads();
    for (int r = 0; r < EB; ++r) {
        const int e = e0 + r;
        if (e >= n_edges) break;
        const float* wrow = wigner + (size_t)e * WIG_ROW;
        float* orow = out + (size_t)rNode[r] * (NKF*32);
        const float* Fr = Ff + r * NOUT;
#pragma unroll
        for (int jj = 0; jj < 4; ++jj) {
            const int p = t + 256*jj;
            if (p < NKF*32) {
                const int k = p >> 5, chh = p & 31;
                float val = 0.f;
#pragma unroll
                for (int m = 0; m < 5; ++m)
                    val = fmaf(wrow[k*WIG_LD+m], Fr[m*32+chh], val);
                atomicAdd(&orow[p], val);
            }
        }
    }
}

// ---------------------------------------------------------------- launch
extern "C" void kernel_launch(void* const* d_in, const int* in_sizes, int n_in,
                              void* d_out, int out_size, void* d_ws, size_t ws_size,
                              hipStream_t stream)
{
    const int*   species     = (const int*)d_in[0];
    const float* edge_embeds = (const float*)d_in[1];
    const int*   senders     = (const int*)d_in[2];
    const int*   receivers   = (const int*)d_in[3];
    const float* wigner      = (const float*)d_in[4];
    const float* embed_table = (const float*)d_in[5];
    const float* W0 = (const float*)d_in[6];
    const float* b0 = (const float*)d_in[7];
    const float* ln0s = (const float*)d_in[8];
    const float* ln0b = (const float*)d_in[9];
    const float* W1 = (const float*)d_in[10];
    const float* b1 = (const float*)d_in[11];
    const float* ln1s = (const float*)d_in[12];
    const float* ln1b = (const float*)d_in[13];
    const float* W2 = (const float*)d_in[14];
    const float* b2 = (const float*)d_in[15];
    float* out = (float*)d_out;

    const int n_nodes = in_sizes[0];
    const int n_edges = in_sizes[2];

    const size_t wpBytes   = WPBYTES;
    const size_t fBytes    = (size_t)n_edges * NOUT * sizeof(float);
    const size_t offBytes  = (size_t)(n_nodes + 1) * sizeof(int);
    const size_t curBytes  = (size_t)n_nodes * sizeof(int);
    const size_t listBytes = (size_t)n_edges * sizeof(int);
    const size_t need = wpBytes + fBytes + offBytes + curBytes + listBytes + 64;

    if (ws_size < need || n_nodes > SCAN_T * SCAN_CH || n_edges <= 0) {
        hipMemsetAsync(out, 0, (size_t)out_size * sizeof(float), stream);
        const int nblocks = (n_edges + EB - 1) / EB;
        hipLaunchKernelGGL(edge_fused_kernel, dim3(nblocks), dim3(256), 0, stream,
                           species, edge_embeds, senders, receivers, wigner, embed_table,
                           W0, b0, ln0s, ln0b, W1, b1, ln1s, ln1b, W2, b2, out, n_edges);
        return;
    }

    char* ws = (char*)d_ws;
    unsigned short* Wp = (unsigned short*)ws;
    float* F       = (float*)(ws + wpBytes);
    int*   offsets = (int*)(ws + wpBytes + fBytes);
    int*   cursor  = (int*)(ws + wpBytes + fBytes + offBytes);
    int*   elist   = (int*)(ws + wpBytes + fBytes + offBytes + curBytes);

    const int egrid = (n_edges + 255) / 256;

    // weight repack (tiny; L2-resident afterwards)
    hipLaunchKernelGGL(repack_w, dim3(336), dim3(256), 0, stream, W0, W1, W2, Wp);

    // CSR build (scan also initializes cursor)
    hipMemsetAsync(cursor, 0, curBytes, stream);
    hipLaunchKernelGGL(hist_kernel, dim3(egrid), dim3(256), 0, stream,
                       receivers, cursor, n_edges);
    hipLaunchKernelGGL(scan_kernel, dim3(1), dim3(SCAN_T), 0, stream,
                       cursor, offsets, cursor, n_nodes);
    hipLaunchKernelGGL(scatter_kernel, dim3(egrid), dim3(256), 0, stream,
                       receivers, cursor, elist, n_edges);

    // MLP (MFMA, round-3 numerics, MB=32 / 4 blocks/CU) -> F
    const int mblocks = (n_edges + MB - 1) / MB;
    hipLaunchKernelGGL(mlp_mfma, dim3(mblocks), dim3(MTHREADS), 0, stream,
                       species, edge_embeds, senders, receivers, embed_table,
                       (const char*)Wp, b0, ln0s, ln0b, b1, ln1s, ln1b, b2, F, n_edges);

    // gather-aggregate -> out (128 thr/node)
    hipLaunchKernelGGL(agg_kernel, dim3(n_nodes), dim3(128), 0, stream,
                       wigner, F, offsets, elist, out);
}